// Round 1
// baseline (515.266 us; speedup 1.0000x reference)
//
#include <hip/hip_runtime.h>
#include <cstdint>

typedef _Float16 f16;
typedef f16 f16x4 __attribute__((ext_vector_type(4)));
typedef f16 f16x8 __attribute__((ext_vector_type(8)));
typedef float f32x4 __attribute__((ext_vector_type(4)));

#define MFMA16(a, b, c) __builtin_amdgcn_mfma_f32_16x16x32_f16(a, b, c, 0, 0, 0)

static __device__ __forceinline__ void gload16(const void* g, void* l) {
    __builtin_amdgcn_global_load_lds(
        (const __attribute__((address_space(1))) uint32_t*)g,
        (__attribute__((address_space(3))) uint32_t*)l, 16, 0, 0);
}

static __device__ __forceinline__ float blockReduceSum256(float v) {
    __shared__ float red[4];
#pragma unroll
    for (int off = 32; off > 0; off >>= 1) v += __shfl_xor(v, off);
    if ((threadIdx.x & 63) == 0) red[threadIdx.x >> 6] = v;
    __syncthreads();
    return red[0] + red[1] + red[2] + red[3];
}

// ---- rmsnorm(x f32, D=1024) -> f16 ----
__global__ __launch_bounds__(256) void k_rmsnorm_x(const float* __restrict__ x,
                                                   const float* __restrict__ gamma,
                                                   f16* __restrict__ out) {
    size_t row = blockIdx.x;
    const float4 v = reinterpret_cast<const float4*>(x + row * 1024)[threadIdx.x];
    float ss = v.x * v.x + v.y * v.y + v.z * v.z + v.w * v.w;
    ss = blockReduceSum256(ss);
    float sc = 32.0f / fmaxf(sqrtf(ss), 1e-12f);  // sqrt(1024)=32
    const float4 g = reinterpret_cast<const float4*>(gamma)[threadIdx.x];
    f16x4 o;
    o[0] = (f16)(v.x * sc * g.x); o[1] = (f16)(v.y * sc * g.y);
    o[2] = (f16)(v.z * sc * g.z); o[3] = (f16)(v.w * sc * g.w);
    *reinterpret_cast<f16x4*>(out + row * 1024 + threadIdx.x * 4) = o;
}

// ---- rmsnorm over f16 rows (in-place safe), D = 4096 or 2048 ----
template <int D>
__global__ __launch_bounds__(256) void k_rmsnorm_f16(const f16* __restrict__ in,
                                                     f16* __restrict__ out,
                                                     const float* __restrict__ gamma) {
    constexpr int PER = D / 256;
    size_t row = blockIdx.x;
    const f16* ir = in + row * D;
    int c0 = threadIdx.x * PER;
    float v[PER];
    float ss = 0.f;
#pragma unroll
    for (int i = 0; i < PER; i += 8) {
        f16x8 h = *reinterpret_cast<const f16x8*>(ir + c0 + i);
#pragma unroll
        for (int e = 0; e < 8; ++e) { float f = (float)h[e]; v[i + e] = f; ss += f * f; }
    }
    ss = blockReduceSum256(ss);
    float sc = sqrtf((float)D) / fmaxf(sqrtf(ss), 1e-12f);
    f16* orow = out + row * D;
#pragma unroll
    for (int i = 0; i < PER; i += 8) {
        f16x8 h;
#pragma unroll
        for (int e = 0; e < 8; ++e) h[e] = (f16)(v[i + e] * sc * gamma[c0 + i + e]);
        *reinterpret_cast<f16x8*>(orow + c0 + i) = h;
    }
}

// ---- f32 -> f16 cast (weights), n4 = n/4 ----
__global__ __launch_bounds__(256) void k_cast(const float* __restrict__ in,
                                              f16* __restrict__ out, int n4) {
    int i = blockIdx.x * 256 + threadIdx.x;
    if (i >= n4) return;
    float4 v = reinterpret_cast<const float4*>(in)[i];
    f16x4 o; o[0] = (f16)v.x; o[1] = (f16)v.y; o[2] = (f16)v.z; o[3] = (f16)v.w;
    *reinterpret_cast<f16x4*>(out + (size_t)i * 4) = o;
}

// ---- C[M,N] = A[M,K] @ Bt[N,K]^T + bias ; EPI: 0 f16, 1 silu->f16, 2 silu->f32 ----
template <int EPI>
__global__ __launch_bounds__(256) void k_gemm_bt(const f16* __restrict__ A,
                                                 const f16* __restrict__ Bt,
                                                 const float* __restrict__ bias,
                                                 void* __restrict__ Cout,
                                                 int M, int N, int K) {
    __shared__ alignas(16) f16 As[128 * 64];
    __shared__ alignas(16) f16 Bs[128 * 64];
    const int bn = blockIdx.x, bm = blockIdx.y;
    const int tid = threadIdx.x;
    const int w = tid >> 6, l = tid & 63;
    const int wr = w >> 1, wc = w & 1;
    const int srow = w * 8 + (l >> 3);
    const int scol = (l & 7) * 8;
    const f16* Ab = A + (size_t)bm * 128 * K;
    const f16* Bb = Bt + (size_t)bn * 128 * K;
    const int lrow = l & 15;
    const int lk = (l >> 4) * 8;
    f32x4 acc[4][4] = {};
    for (int k0 = 0; k0 < K; k0 += 64) {
#pragma unroll
        for (int i = 0; i < 4; ++i)
            gload16(Ab + (size_t)(i * 32 + srow) * K + k0 + scol, &As[(i * 32 + w * 8) * 64]);
#pragma unroll
        for (int i = 0; i < 4; ++i)
            gload16(Bb + (size_t)(i * 32 + srow) * K + k0 + scol, &Bs[(i * 32 + w * 8) * 64]);
        __syncthreads();  // compiler drains vmcnt before barrier
#pragma unroll
        for (int kk = 0; kk < 64; kk += 32) {
            f16x8 a[4], b[4];
#pragma unroll
            for (int m = 0; m < 4; ++m)
                a[m] = *reinterpret_cast<const f16x8*>(&As[(wr * 64 + m * 16 + lrow) * 64 + kk + lk]);
#pragma unroll
            for (int n = 0; n < 4; ++n)
                b[n] = *reinterpret_cast<const f16x8*>(&Bs[(wc * 64 + n * 16 + lrow) * 64 + kk + lk]);
#pragma unroll
            for (int m = 0; m < 4; ++m)
#pragma unroll
                for (int n = 0; n < 4; ++n)
                    acc[m][n] = MFMA16(a[m], b[n], acc[m][n]);
        }
        __syncthreads();
    }
    const int row0 = bm * 128 + wr * 64;
    const int col0 = bn * 128 + wc * 64;
    const int lr4 = (l >> 4) * 4;
#pragma unroll
    for (int n = 0; n < 4; ++n) {
        const int col = col0 + n * 16 + lrow;
        const float bs = bias[col];
#pragma unroll
        for (int m = 0; m < 4; ++m) {
#pragma unroll
            for (int r = 0; r < 4; ++r) {
                const int row = row0 + m * 16 + lr4 + r;
                float v = acc[m][n][r] + bs;
                if (EPI >= 1) v = v / (1.f + __expf(-v));
                if (EPI == 2)
                    reinterpret_cast<float*>(Cout)[(size_t)row * N + col] = v;
                else
                    reinterpret_cast<f16*>(Cout)[(size_t)row * N + col] = (f16)v;
            }
        }
    }
}

// ---- windowed GQA attention: one block per (b, g, s); 4 waves x 2 heads ----
__global__ __launch_bounds__(256) void k_attn(const f16* __restrict__ q,
                                              const f16* __restrict__ kv,
                                              f16* __restrict__ o) {
    __shared__ alignas(16) f16 Ksm[64 * 64];
    __shared__ alignas(16) f16 Vtsm[64 * 64];
    __shared__ alignas(16) f16 Psm[4][64 * 64];
    const int idx = blockIdx.x;
    const int s = idx & 127;
    const int g = (idx >> 7) & 7;
    const int b = idx >> 10;
    const int tid = threadIdx.x;
    const int w = tid >> 6, l = tid & 63;

    // load K window [64][64] and V^T [64][64]
    const int baseR = s * 32 - 16;
#pragma unroll
    for (int i = 0; i < 2; ++i) {
        const int j = i * 32 + (tid >> 3);
        const int d0 = (tid & 7) * 8;
        const int R = baseR + j;
        f16x8 kvv = {}, vvv = {};
        if (R >= 0 && R < 4096) {
            const f16* rp = kv + ((size_t)(b * 4096 + R)) * 1024 + g * 64 + d0;
            kvv = *reinterpret_cast<const f16x8*>(rp);
            vvv = *reinterpret_cast<const f16x8*>(rp + 512);
        }
        *reinterpret_cast<f16x8*>(&Ksm[j * 64 + d0]) = kvv;
#pragma unroll
        for (int e = 0; e < 8; ++e) Vtsm[(d0 + e) * 64 + j] = vvv[e];
    }

    // Q fragments straight from global: wave w owns q-rows w*64 .. w*64+63 (heads 2w, 2w+1)
    const int lrow = l & 15, lk = (l >> 4) * 8;
    f16x8 aq[4][2];
#pragma unroll
    for (int m = 0; m < 4; ++m) {
        const int qr = w * 64 + m * 16 + lrow;
        const int h = qr >> 5, qi = qr & 31;
        const f16* qp = q + ((size_t)(b * 4096 + s * 32 + qi)) * 4096 + (g * 8 + h) * 64 + lk;
        aq[m][0] = *reinterpret_cast<const f16x8*>(qp);
        aq[m][1] = *reinterpret_cast<const f16x8*>(qp + 32);
    }
    __syncthreads();

    // QK^T: [64 q-rows] x [64 k-cols]
    f32x4 acc[4][4] = {};
#pragma unroll
    for (int kk = 0; kk < 2; ++kk) {
        f16x8 bk[4];
#pragma unroll
        for (int n = 0; n < 4; ++n)
            bk[n] = *reinterpret_cast<const f16x8*>(&Ksm[(n * 16 + lrow) * 64 + kk * 32 + lk]);
#pragma unroll
        for (int m = 0; m < 4; ++m)
#pragma unroll
            for (int n = 0; n < 4; ++n)
                acc[m][n] = MFMA16(aq[m][kk], bk[n], acc[m][n]);
    }

    // masked softmax over 64 k-cols; mask = whole 16-col tile at the edges
    const int nlo = (s == 0) ? 1 : 0;
    const int nhi = (s == 127) ? 3 : 4;
#pragma unroll
    for (int m = 0; m < 4; ++m) {
#pragma unroll
        for (int r = 0; r < 4; ++r) {
            float xv[4];
#pragma unroll
            for (int n = 0; n < 4; ++n) xv[n] = acc[m][n][r] * 0.125f;  // 1/sqrt(64)
            float mx = -1e30f;
            for (int n = nlo; n < nhi; ++n) mx = fmaxf(mx, xv[n]);
#pragma unroll
            for (int off = 8; off > 0; off >>= 1) mx = fmaxf(mx, __shfl_xor(mx, off));
            float pv[4]; float sum = 0.f;
#pragma unroll
            for (int n = 0; n < 4; ++n) {
                float e = (n >= nlo && n < nhi) ? __expf(xv[n] - mx) : 0.f;
                pv[n] = e; sum += e;
            }
#pragma unroll
            for (int off = 8; off > 0; off >>= 1) sum += __shfl_xor(sum, off);
            const float inv = 1.f / sum;
            const int prow = m * 16 + (l >> 4) * 4 + r;
#pragma unroll
            for (int n = 0; n < 4; ++n)
                Psm[w][prow * 64 + n * 16 + lrow] = (f16)(pv[n] * inv);
        }
    }
    __syncthreads();

    // PV: o[64 q-rows][64 d]
    f32x4 oacc[4][4] = {};
#pragma unroll
    for (int kk = 0; kk < 2; ++kk) {
        f16x8 ap[4], bv[4];
#pragma unroll
        for (int m = 0; m < 4; ++m)
            ap[m] = *reinterpret_cast<const f16x8*>(&Psm[w][(m * 16 + lrow) * 64 + kk * 32 + lk]);
#pragma unroll
        for (int n = 0; n < 4; ++n)
            bv[n] = *reinterpret_cast<const f16x8*>(&Vtsm[(n * 16 + lrow) * 64 + kk * 32 + lk]);
#pragma unroll
        for (int m = 0; m < 4; ++m)
#pragma unroll
            for (int n = 0; n < 4; ++n)
                oacc[m][n] = MFMA16(ap[m], bv[n], oacc[m][n]);
    }
    const int lr4 = (l >> 4) * 4;
#pragma unroll
    for (int m = 0; m < 4; ++m) {
#pragma unroll
        for (int r = 0; r < 4; ++r) {
            const int qr = w * 64 + m * 16 + lr4 + r;
            const int h = qr >> 5, qi = qr & 31;
            f16* op = o + ((size_t)(b * 4096 + s * 32 + qi)) * 4096 + (g * 8 + h) * 64;
#pragma unroll
            for (int n = 0; n < 4; ++n) op[n * 16 + lrow] = (f16)oacc[m][n][r];
        }
    }
}

extern "C" void kernel_launch(void* const* d_in, const int* in_sizes, int n_in,
                              void* d_out, int out_size, void* d_ws, size_t ws_size,
                              hipStream_t stream) {
    const float* x     = (const float*)d_in[0];
    const float* ng    = (const float*)d_in[1];
    const float* Wq_w  = (const float*)d_in[2];
    const float* Wq_b  = (const float*)d_in[3];
    const float* Wkv_w = (const float*)d_in[4];
    const float* Wkv_b = (const float*)d_in[5];
    const float* g1    = (const float*)d_in[6];
    const float* W1_w  = (const float*)d_in[7];
    const float* W1_b  = (const float*)d_in[8];
    const float* g2    = (const float*)d_in[9];
    const float* W2_w  = (const float*)d_in[10];
    const float* W2_b  = (const float*)d_in[11];
    float* out = (float*)d_out;

    char* p = (char*)d_ws;
    f16* xn  = (f16*)p; p += (size_t)8192 * 1024 * 2;
    f16* wq  = (f16*)p; p += (size_t)4096 * 1024 * 2;
    f16* wkv = (f16*)p; p += (size_t)1024 * 1024 * 2;
    f16* w1  = (f16*)p; p += (size_t)2048 * 4096 * 2;
    f16* w2  = (f16*)p; p += (size_t)1024 * 2048 * 2;
    f16* qb  = (f16*)p; p += (size_t)8192 * 4096 * 2;  // later reused as h1
    f16* kvb = (f16*)p; p += (size_t)8192 * 1024 * 2;
    f16* ob  = (f16*)p; p += (size_t)8192 * 4096 * 2;
    f16* h1  = qb;

    k_cast<<<4096, 256, 0, stream>>>(Wq_w, wq, 4096 * 1024 / 4);
    k_cast<<<1024, 256, 0, stream>>>(Wkv_w, wkv, 1024 * 1024 / 4);
    k_cast<<<8192, 256, 0, stream>>>(W1_w, w1, 2048 * 4096 / 4);
    k_cast<<<2048, 256, 0, stream>>>(W2_w, w2, 1024 * 2048 / 4);
    k_rmsnorm_x<<<8192, 256, 0, stream>>>(x, ng, xn);

    k_gemm_bt<0><<<dim3(32, 64), 256, 0, stream>>>(xn, wq, Wq_b, qb, 8192, 4096, 1024);
    k_gemm_bt<0><<<dim3(8, 64), 256, 0, stream>>>(xn, wkv, Wkv_b, kvb, 8192, 1024, 1024);

    k_attn<<<2048, 256, 0, stream>>>(qb, kvb, ob);

    k_rmsnorm_f16<4096><<<8192, 256, 0, stream>>>(ob, ob, g1);
    k_gemm_bt<1><<<dim3(16, 64), 256, 0, stream>>>(ob, w1, W1_b, h1, 8192, 2048, 4096);
    k_rmsnorm_f16<2048><<<8192, 256, 0, stream>>>(h1, h1, g2);
    k_gemm_bt<2><<<dim3(8, 64), 256, 0, stream>>>(h1, w2, W2_b, (void*)out, 8192, 1024, 2048);

    (void)in_sizes; (void)n_in; (void)out_size; (void)ws_size;
}

// Round 2
// 432.891 us; speedup vs baseline: 1.1903x; 1.1903x over previous
//
#include <hip/hip_runtime.h>
#include <cstdint>

typedef _Float16 f16;
typedef f16 f16x4 __attribute__((ext_vector_type(4)));
typedef f16 f16x8 __attribute__((ext_vector_type(8)));
typedef float f32x4 __attribute__((ext_vector_type(4)));

#define MFMA16(a, b, c) __builtin_amdgcn_mfma_f32_16x16x32_f16(a, b, c, 0, 0, 0)

static __device__ __forceinline__ void gload16(const void* g, void* l) {
    __builtin_amdgcn_global_load_lds(
        (const __attribute__((address_space(1))) uint32_t*)g,
        (__attribute__((address_space(3))) uint32_t*)l, 16, 0, 0);
}

static __device__ __forceinline__ float blockReduceSum256(float v) {
    __shared__ float red[4];
#pragma unroll
    for (int off = 32; off > 0; off >>= 1) v += __shfl_xor(v, off);
    if ((threadIdx.x & 63) == 0) red[threadIdx.x >> 6] = v;
    __syncthreads();
    return red[0] + red[1] + red[2] + red[3];
}

// ---- rmsnorm(x f32, D=1024) -> f16 ----
__global__ __launch_bounds__(256) void k_rmsnorm_x(const float* __restrict__ x,
                                                   const float* __restrict__ gamma,
                                                   f16* __restrict__ out) {
    size_t row = blockIdx.x;
    const float4 v = reinterpret_cast<const float4*>(x + row * 1024)[threadIdx.x];
    float ss = v.x * v.x + v.y * v.y + v.z * v.z + v.w * v.w;
    ss = blockReduceSum256(ss);
    float sc = 32.0f / fmaxf(sqrtf(ss), 1e-12f);
    const float4 g = reinterpret_cast<const float4*>(gamma)[threadIdx.x];
    f16x4 o;
    o[0] = (f16)(v.x * sc * g.x); o[1] = (f16)(v.y * sc * g.y);
    o[2] = (f16)(v.z * sc * g.z); o[3] = (f16)(v.w * sc * g.w);
    *reinterpret_cast<f16x4*>(out + row * 1024 + threadIdx.x * 4) = o;
}

// ---- rmsnorm over f16 rows (in-place safe), D = 4096 or 2048 ----
template <int D>
__global__ __launch_bounds__(256) void k_rmsnorm_f16(const f16* __restrict__ in,
                                                     f16* __restrict__ out,
                                                     const float* __restrict__ gamma) {
    constexpr int PER = D / 256;
    size_t row = blockIdx.x;
    const f16* ir = in + row * D;
    int c0 = threadIdx.x * PER;
    float v[PER];
    float ss = 0.f;
#pragma unroll
    for (int i = 0; i < PER; i += 8) {
        f16x8 h = *reinterpret_cast<const f16x8*>(ir + c0 + i);
#pragma unroll
        for (int e = 0; e < 8; ++e) { float f = (float)h[e]; v[i + e] = f; ss += f * f; }
    }
    ss = blockReduceSum256(ss);
    float sc = sqrtf((float)D) / fmaxf(sqrtf(ss), 1e-12f);
    f16* orow = out + row * D;
#pragma unroll
    for (int i = 0; i < PER; i += 8) {
        f16x8 h;
#pragma unroll
        for (int e = 0; e < 8; ++e) h[e] = (f16)(v[i + e] * sc * gamma[c0 + i + e]);
        *reinterpret_cast<f16x8*>(orow + c0 + i) = h;
    }
}

// ---- f32 -> f16 cast (weights), n4 = n/4 ----
__global__ __launch_bounds__(256) void k_cast(const float* __restrict__ in,
                                              f16* __restrict__ out, int n4) {
    int i = blockIdx.x * 256 + threadIdx.x;
    if (i >= n4) return;
    float4 v = reinterpret_cast<const float4*>(in)[i];
    f16x4 o; o[0] = (f16)v.x; o[1] = (f16)v.y; o[2] = (f16)v.z; o[3] = (f16)v.w;
    *reinterpret_cast<f16x4*>(out + (size_t)i * 4) = o;
}

// ---- bias concat: [0,4096) from a, [4096,5120) from b ----
__global__ __launch_bounds__(256) void k_bias_cat(const float* __restrict__ a,
                                                  const float* __restrict__ b,
                                                  float* __restrict__ o) {
    int i = blockIdx.x * 256 + threadIdx.x;
    o[i] = (i < 4096) ? a[i] : b[i - 4096];
}

// ==== 256-wide deep-pipelined GEMM: C[M,N] = A[M,K] @ Bt[N,K]^T + bias ====
// BM=256, BK=32, 512 threads (8 waves). 4-deep LDS ring, counted vmcnt (never
// drains in main loop), XOR-swizzled LDS via pre-swizzled global source.
// EPI: 0 f16, 1 silu->f16, 2 silu->f32
template <int BN, int EPI>
__global__ __launch_bounds__(512, 2) void k_gemm256(const f16* __restrict__ A,
                                                    const f16* __restrict__ Bt,
                                                    const float* __restrict__ bias,
                                                    void* __restrict__ Cout,
                                                    int M, int N, int K) {
    constexpr int BM = 256;
    constexpr int WN = BN / 64;       // waves along N (4 or 2)
    constexpr int WM = 8 / WN;        // waves along M (2 or 4)
    constexpr int WR = BM / WM;       // wave rows (128 or 64)
    constexpr int MW = WR / 16;       // A frags per wave (8 or 4)
    constexpr int ASI = 2;            // A stage issues/thread (256*64B / 8KB)
    constexpr int BSI = BN / 128;     // B stage issues/thread
    constexpr int SPT = ASI + BSI;    // gloads per tile per thread
    constexpr int AE = BM * 32;       // A elems per tile slot
    constexpr int BE = BN * 32;
    constexpr int TE = AE + BE;

    __shared__ f16 lds[4 * TE];       // 128 KB (BN=256) or 96 KB (BN=128)

    const int mb = M / BM;
    const int nwg = (N / BN) * mb;
    int wg = blockIdx.x;
    wg = (wg & 7) * (nwg >> 3) + (wg >> 3);   // XCD swizzle (nwg % 8 == 0)
    const int bn = wg / mb, bm = wg % mb;

    const int tid = threadIdx.x;
    const int w = tid >> 6, l = tid & 63;
    const int wm = w / WN, wn = w % WN;
    const int lrow = l & 15, lq = l >> 4;

    const f16* Ab = A + (size_t)bm * BM * K;
    const f16* Bb = Bt + (size_t)bn * BN * K;
    const int NT = K >> 5;

    // swizzle: LDS[r][slot s] holds global k-chunk (s ^ f(r)), f(r)=(r+(r>>2))&3
    // stage: linear LDS dest + permuted global col; read: slot = q ^ f(r)
    int ar[ASI], ac[ASI], br[BSI], bc[BSI];
#pragma unroll
    for (int i = 0; i < ASI; ++i) {
        int r = i * 128 + w * 16 + (l >> 2);
        ar[i] = r; ac[i] = 8 * ((l & 3) ^ ((r + (r >> 2)) & 3));
    }
#pragma unroll
    for (int j = 0; j < BSI; ++j) {
        int r = j * 128 + w * 16 + (l >> 2);
        br[j] = r; bc[j] = 8 * ((l & 3) ^ ((r + (r >> 2)) & 3));
    }
    int aoff[MW], boff[4];
#pragma unroll
    for (int m = 0; m < MW; ++m) {
        int r = wm * WR + m * 16 + lrow;
        aoff[m] = r * 32 + 8 * (lq ^ ((r + (r >> 2)) & 3));
    }
#pragma unroll
    for (int n = 0; n < 4; ++n) {
        int r = wn * 64 + n * 16 + lrow;
        boff[n] = AE + r * 32 + 8 * (lq ^ ((r + (r >> 2)) & 3));
    }

#define STAGE(t) {                                                          \
    const int _b = (t) & 3; const int _k0 = (t) << 5;                       \
    _Pragma("unroll") for (int i = 0; i < ASI; ++i)                         \
        gload16(Ab + (size_t)ar[i] * K + _k0 + ac[i],                       \
                &lds[_b * TE + i * 4096 + w * 512]);                        \
    _Pragma("unroll") for (int j = 0; j < BSI; ++j)                         \
        gload16(Bb + (size_t)br[j] * K + _k0 + bc[j],                       \
                &lds[_b * TE + AE + j * 4096 + w * 512]);                   \
}

    f32x4 acc[MW][4] = {};

    STAGE(0); STAGE(1); STAGE(2);
    for (int t = 0; t < NT; ++t) {
        if (t < NT - 2)
            asm volatile("s_waitcnt vmcnt(%0)" :: "i"(2 * SPT) : "memory");
        else if (t == NT - 2)
            asm volatile("s_waitcnt vmcnt(%0)" :: "i"(SPT) : "memory");
        else
            asm volatile("s_waitcnt vmcnt(0)" ::: "memory");
        __builtin_amdgcn_s_barrier();
        __builtin_amdgcn_sched_barrier(0);
        if (t + 3 < NT) STAGE(t + 3);
        {
            const f16* base = &lds[(t & 3) * TE];
            f16x8 af[MW], bf[4];
#pragma unroll
            for (int m = 0; m < MW; ++m)
                af[m] = *reinterpret_cast<const f16x8*>(base + aoff[m]);
#pragma unroll
            for (int n = 0; n < 4; ++n)
                bf[n] = *reinterpret_cast<const f16x8*>(base + boff[n]);
            __builtin_amdgcn_s_setprio(1);
#pragma unroll
            for (int m = 0; m < MW; ++m)
#pragma unroll
                for (int n = 0; n < 4; ++n)
                    acc[m][n] = MFMA16(af[m], bf[n], acc[m][n]);
            __builtin_amdgcn_s_setprio(0);
        }
    }
#undef STAGE

    const size_t row0 = (size_t)bm * BM + wm * WR;
    const int col0 = bn * BN + wn * 64;
    const int lr4 = lq * 4;
#pragma unroll
    for (int n = 0; n < 4; ++n) {
        const int col = col0 + n * 16 + lrow;
        const float bs = bias[col];
#pragma unroll
        for (int m = 0; m < MW; ++m) {
#pragma unroll
            for (int r = 0; r < 4; ++r) {
                const size_t row = row0 + m * 16 + lr4 + r;
                float v = acc[m][n][r] + bs;
                if (EPI >= 1) v = v / (1.f + __expf(-v));
                if (EPI == 2)
                    reinterpret_cast<float*>(Cout)[row * N + col] = v;
                else
                    reinterpret_cast<f16*>(Cout)[row * N + col] = (f16)v;
            }
        }
    }
}

// ---- windowed GQA attention from combined QKV buffer (row stride 5120) ----
// q cols [0,4096); k cols [4096,4608); v cols [4608,5120)
__global__ __launch_bounds__(256) void k_attn(const f16* __restrict__ qkv,
                                              f16* __restrict__ o) {
    __shared__ alignas(16) f16 Ksm[64 * 64];
    __shared__ alignas(16) f16 Vtsm[64 * 64];
    __shared__ alignas(16) f16 Psm[4][64 * 64];
    const int idx = blockIdx.x;
    const int s = idx & 127;
    const int g = (idx >> 7) & 7;
    const int b = idx >> 10;
    const int tid = threadIdx.x;
    const int w = tid >> 6, l = tid & 63;

    const int baseR = s * 32 - 16;
#pragma unroll
    for (int i = 0; i < 2; ++i) {
        const int j = i * 32 + (tid >> 3);
        const int d0 = (tid & 7) * 8;
        const int R = baseR + j;
        f16x8 kvv = {}, vvv = {};
        if (R >= 0 && R < 4096) {
            const f16* rp = qkv + ((size_t)(b * 4096 + R)) * 5120 + 4096 + g * 64 + d0;
            kvv = *reinterpret_cast<const f16x8*>(rp);
            vvv = *reinterpret_cast<const f16x8*>(rp + 512);
        }
        *reinterpret_cast<f16x8*>(&Ksm[j * 64 + d0]) = kvv;
#pragma unroll
        for (int e = 0; e < 8; ++e) Vtsm[(d0 + e) * 64 + j] = vvv[e];
    }

    const int lrow = l & 15, lk = (l >> 4) * 8;
    f16x8 aq[4][2];
#pragma unroll
    for (int m = 0; m < 4; ++m) {
        const int qr = w * 64 + m * 16 + lrow;
        const int h = qr >> 5, qi = qr & 31;
        const f16* qp = qkv + ((size_t)(b * 4096 + s * 32 + qi)) * 5120 + (g * 8 + h) * 64 + lk;
        aq[m][0] = *reinterpret_cast<const f16x8*>(qp);
        aq[m][1] = *reinterpret_cast<const f16x8*>(qp + 32);
    }
    __syncthreads();

    f32x4 acc[4][4] = {};
#pragma unroll
    for (int kk = 0; kk < 2; ++kk) {
        f16x8 bk[4];
#pragma unroll
        for (int n = 0; n < 4; ++n)
            bk[n] = *reinterpret_cast<const f16x8*>(&Ksm[(n * 16 + lrow) * 64 + kk * 32 + lk]);
#pragma unroll
        for (int m = 0; m < 4; ++m)
#pragma unroll
            for (int n = 0; n < 4; ++n)
                acc[m][n] = MFMA16(aq[m][kk], bk[n], acc[m][n]);
    }

    const int nlo = (s == 0) ? 1 : 0;
    const int nhi = (s == 127) ? 3 : 4;
#pragma unroll
    for (int m = 0; m < 4; ++m) {
#pragma unroll
        for (int r = 0; r < 4; ++r) {
            float xv[4];
#pragma unroll
            for (int n = 0; n < 4; ++n) xv[n] = acc[m][n][r] * 0.125f;
            float mx = -1e30f;
            for (int n = nlo; n < nhi; ++n) mx = fmaxf(mx, xv[n]);
#pragma unroll
            for (int off = 8; off > 0; off >>= 1) mx = fmaxf(mx, __shfl_xor(mx, off));
            float pv[4]; float sum = 0.f;
#pragma unroll
            for (int n = 0; n < 4; ++n) {
                float e = (n >= nlo && n < nhi) ? __expf(xv[n] - mx) : 0.f;
                pv[n] = e; sum += e;
            }
#pragma unroll
            for (int off = 8; off > 0; off >>= 1) sum += __shfl_xor(sum, off);
            const float inv = 1.f / sum;
            const int prow = m * 16 + (l >> 4) * 4 + r;
#pragma unroll
            for (int n = 0; n < 4; ++n)
                Psm[w][prow * 64 + n * 16 + lrow] = (f16)(pv[n] * inv);
        }
    }
    __syncthreads();

    f32x4 oacc[4][4] = {};
#pragma unroll
    for (int kk = 0; kk < 2; ++kk) {
        f16x8 ap[4], bv[4];
#pragma unroll
        for (int m = 0; m < 4; ++m)
            ap[m] = *reinterpret_cast<const f16x8*>(&Psm[w][(m * 16 + lrow) * 64 + kk * 32 + lk]);
#pragma unroll
        for (int n = 0; n < 4; ++n)
            bv[n] = *reinterpret_cast<const f16x8*>(&Vtsm[(n * 16 + lrow) * 64 + kk * 32 + lk]);
#pragma unroll
        for (int m = 0; m < 4; ++m)
#pragma unroll
            for (int n = 0; n < 4; ++n)
                oacc[m][n] = MFMA16(ap[m], bv[n], oacc[m][n]);
    }
    const int lr4 = (l >> 4) * 4;
#pragma unroll
    for (int m = 0; m < 4; ++m) {
#pragma unroll
        for (int r = 0; r < 4; ++r) {
            const int qr = w * 64 + m * 16 + lr4 + r;
            const int h = qr >> 5, qi = qr & 31;
            f16* op = o + ((size_t)(b * 4096 + s * 32 + qi)) * 4096 + (g * 8 + h) * 64;
#pragma unroll
            for (int n = 0; n < 4; ++n) op[n * 16 + lrow] = (f16)oacc[m][n][r];
        }
    }
}

extern "C" void kernel_launch(void* const* d_in, const int* in_sizes, int n_in,
                              void* d_out, int out_size, void* d_ws, size_t ws_size,
                              hipStream_t stream) {
    const float* x     = (const float*)d_in[0];
    const float* ng    = (const float*)d_in[1];
    const float* Wq_w  = (const float*)d_in[2];
    const float* Wq_b  = (const float*)d_in[3];
    const float* Wkv_w = (const float*)d_in[4];
    const float* Wkv_b = (const float*)d_in[5];
    const float* g1    = (const float*)d_in[6];
    const float* W1_w  = (const float*)d_in[7];
    const float* W1_b  = (const float*)d_in[8];
    const float* g2    = (const float*)d_in[9];
    const float* W2_w  = (const float*)d_in[10];
    const float* W2_b  = (const float*)d_in[11];
    float* out = (float*)d_out;

    // lifetime-overlapped workspace (peak ~164 MB)
    char* p = (char*)d_ws;
    f16* qkv  = (f16*)(p);                          // [8192][5120]  80 MB   [QKV, attn)
    f16* ob   = (f16*)(p + 83886080);               // [8192][4096]  64 MB   [attn, FF1)
    f16* w1   = (f16*)(p + 150994944);              // [2048][4096]  16 MB
    f16* w2   = (f16*)(p + 167772160);              // [1024][2048]   4 MB
    f16* h1   = (f16*)(p);                          // [8192][2048]  32 MB   (over qkv)
    f16* xn   = (f16*)(p + 83886080);               // [8192][1024]  16 MB   (over ob)
    f16* wqkv = (f16*)(p + 100663296);              // [5120][1024]  10 MB   (over ob)
    float* cb = (float*)(p + 111149056);            // [5120] bias           (over ob)

    k_cast<<<4096, 256, 0, stream>>>(Wq_w, wqkv, 4096 * 1024 / 4);
    k_cast<<<1024, 256, 0, stream>>>(Wkv_w, wqkv + 4096 * 1024, 1024 * 1024 / 4);
    k_cast<<<8192, 256, 0, stream>>>(W1_w, w1, 2048 * 4096 / 4);
    k_cast<<<2048, 256, 0, stream>>>(W2_w, w2, 1024 * 2048 / 4);
    k_bias_cat<<<20, 256, 0, stream>>>(Wq_b, Wkv_b, cb);
    k_rmsnorm_x<<<8192, 256, 0, stream>>>(x, ng, xn);

    // fused Q+KV GEMM: [8192,1024] @ [5120,1024]^T -> [8192,5120]
    k_gemm256<256, 0><<<640, 512, 0, stream>>>(xn, wqkv, cb, qkv, 8192, 5120, 1024);

    k_attn<<<2048, 256, 0, stream>>>(qkv, ob);

    k_rmsnorm_f16<4096><<<8192, 256, 0, stream>>>(ob, ob, g1);
    k_gemm256<256, 1><<<256, 512, 0, stream>>>(ob, w1, W1_b, h1, 8192, 2048, 4096);
    k_rmsnorm_f16<2048><<<8192, 256, 0, stream>>>(h1, h1, g2);
    k_gemm256<128, 2><<<256, 512, 0, stream>>>(h1, w2, W2_b, (void*)out, 8192, 1024, 2048);

    (void)in_sizes; (void)n_in; (void)out_size; (void)ws_size;
}

// Round 3
// 395.434 us; speedup vs baseline: 1.3030x; 1.0947x over previous
//
#include <hip/hip_runtime.h>
#include <cstdint>

typedef _Float16 f16;
typedef f16 f16x4 __attribute__((ext_vector_type(4)));
typedef f16 f16x8 __attribute__((ext_vector_type(8)));
typedef float f32x4 __attribute__((ext_vector_type(4)));

#define MFMA16(a, b, c) __builtin_amdgcn_mfma_f32_16x16x32_f16(a, b, c, 0, 0, 0)

static __device__ __forceinline__ void gload16(const void* g, void* l) {
    __builtin_amdgcn_global_load_lds(
        (const __attribute__((address_space(1))) uint32_t*)g,
        (__attribute__((address_space(3))) uint32_t*)l, 16, 0, 0);
}

static __device__ __forceinline__ float blockReduceSum256(float v) {
    __shared__ float red[4];
#pragma unroll
    for (int off = 32; off > 0; off >>= 1) v += __shfl_xor(v, off);
    if ((threadIdx.x & 63) == 0) red[threadIdx.x >> 6] = v;
    __syncthreads();
    return red[0] + red[1] + red[2] + red[3];
}

// ---- rmsnorm(x f32, D=1024) -> f16 ----
__global__ __launch_bounds__(256) void k_rmsnorm_x(const float* __restrict__ x,
                                                   const float* __restrict__ gamma,
                                                   f16* __restrict__ out) {
    size_t row = blockIdx.x;
    const float4 v = reinterpret_cast<const float4*>(x + row * 1024)[threadIdx.x];
    float ss = v.x * v.x + v.y * v.y + v.z * v.z + v.w * v.w;
    ss = blockReduceSum256(ss);
    float sc = 32.0f / fmaxf(sqrtf(ss), 1e-12f);
    const float4 g = reinterpret_cast<const float4*>(gamma)[threadIdx.x];
    f16x4 o;
    o[0] = (f16)(v.x * sc * g.x); o[1] = (f16)(v.y * sc * g.y);
    o[2] = (f16)(v.z * sc * g.z); o[3] = (f16)(v.w * sc * g.w);
    *reinterpret_cast<f16x4*>(out + row * 1024 + threadIdx.x * 4) = o;
}

// ---- per-row scale: sc[row] = sqrt(D)/max(||row||,1e-12) ----
template <int D>
__global__ __launch_bounds__(256) void k_rowss(const f16* __restrict__ in,
                                               float* __restrict__ sc) {
    constexpr int PER = D / 256;
    size_t row = blockIdx.x;
    const f16* ir = in + row * D;
    int c0 = threadIdx.x * PER;
    float ss = 0.f;
#pragma unroll
    for (int i = 0; i < PER; i += 8) {
        f16x8 h = *reinterpret_cast<const f16x8*>(ir + c0 + i);
#pragma unroll
        for (int e = 0; e < 8; ++e) { float f = (float)h[e]; ss += f * f; }
    }
    ss = blockReduceSum256(ss);
    if (threadIdx.x == 0)
        sc[row] = sqrtf((float)D) / fmaxf(sqrtf(ss), 1e-12f);
}

// ---- f32 -> f16 cast ----
__global__ __launch_bounds__(256) void k_cast(const float* __restrict__ in,
                                              f16* __restrict__ out, int n4) {
    int i = blockIdx.x * 256 + threadIdx.x;
    if (i >= n4) return;
    float4 v = reinterpret_cast<const float4*>(in)[i];
    f16x4 o; o[0] = (f16)v.x; o[1] = (f16)v.y; o[2] = (f16)v.z; o[3] = (f16)v.w;
    *reinterpret_cast<f16x4*>(out + (size_t)i * 4) = o;
}

// ---- f32 -> f16 cast with per-column gamma fold (K = kmask+1, pow2) ----
__global__ __launch_bounds__(256) void k_cast_g(const float* __restrict__ in,
                                                f16* __restrict__ out,
                                                const float* __restrict__ gamma,
                                                int kmask, int n4) {
    int i = blockIdx.x * 256 + threadIdx.x;
    if (i >= n4) return;
    float4 v = reinterpret_cast<const float4*>(in)[i];
    int e0 = (i * 4) & kmask;
    f16x4 o;
    o[0] = (f16)(v.x * gamma[e0]); o[1] = (f16)(v.y * gamma[e0 + 1]);
    o[2] = (f16)(v.z * gamma[e0 + 2]); o[3] = (f16)(v.w * gamma[e0 + 3]);
    *reinterpret_cast<f16x4*>(out + (size_t)i * 4) = o;
}

// ---- bias concat ----
__global__ __launch_bounds__(256) void k_bias_cat(const float* __restrict__ a,
                                                  const float* __restrict__ b,
                                                  float* __restrict__ o) {
    int i = blockIdx.x * 256 + threadIdx.x;
    o[i] = (i < 4096) ? a[i] : b[i - 4096];
}

// ==== 4-phase-per-K-tile pipelined GEMM (m201-template port, f16) ====
// C[M,N] = (rowsc ? rowsc[row]*: ) A[M,K]@Bt[N,K]^T + bias ; EPI 0 f16 / 1 silu f16 / 2 silu f32
// BM=256, BK=64, 512 thr (8 waves). 2 LDS slots x {A_K0,A_K1,B_K0,B_K1}.
// Counted vmcnt ledger (see analysis): steady waits = 2*(LA+LB), tail = LA+LB then 0.
template <int BN, int EPI, int MODE>
__global__ __launch_bounds__(512, 2) void k_gemm8p(const f16* __restrict__ A,
                                                   const f16* __restrict__ Bt,
                                                   const float* __restrict__ bias,
                                                   const float* __restrict__ rowsc,
                                                   void* __restrict__ Cout,
                                                   int M, int N, int K) {
    constexpr int BM = 256;
    constexpr int WN = BN / 64, WM = 8 / WN, WR = BM / WM;
    constexpr int MW = WR / 16, MH = MW / 2;
    constexpr int LA = 2, LB = BN / 128;       // gloads per chunk per thread
    constexpr int WSTEADY = 2 * (LA + LB), WTAIL = LA + LB;
    constexpr int AK = BM * 32;                // elems per A K-half region
    constexpr int BKE = BN * 32;
    constexpr int SE = 2 * AK + 2 * BKE;       // slot elems

    __shared__ alignas(16) f16 lds[2 * SE];

    const int nb = N / BN, mb = M / BM;
    int bn, bm;
    if (MODE == 0) { bn = blockIdx.x & 7; bm = blockIdx.x >> 3; }   // nb==8: pin bn per XCD
    else           { bn = blockIdx.x % nb; bm = blockIdx.x / nb; }  // bm-major (L3 stripe)
    (void)mb;

    const int tid = threadIdx.x, w = tid >> 6, l = tid & 63;
    const int wm = w / WN, wn = w % WN;
    const int lrow = l & 15, lq = l >> 4;
    const int g = (lrow >> 1) & 3;             // swizzle: chunk' = chunk ^ g(row)

    const f16* Ab = A + (size_t)bm * BM * K;
    const f16* Bb = Bt + (size_t)bn * BN * K;
    const int NT = K >> 6;

    int aoff[MW], boff[4];
#pragma unroll
    for (int m = 0; m < MW; ++m)
        aoff[m] = (wm * WR + m * 16 + lrow) * 32 + 8 * (lq ^ g);
#pragma unroll
    for (int n = 0; n < 4; ++n)
        boff[n] = (wn * 64 + n * 16 + lrow) * 32 + 8 * (lq ^ g);

    auto stageA = [&](int k0, f16* region) {
#pragma unroll
        for (int q = 0; q < LA; ++q) {
            int r = q * 128 + w * 16 + (l >> 2);
            int c = 8 * ((l & 3) ^ ((r >> 1) & 3));
            gload16(Ab + (size_t)r * K + k0 + c, region + q * 4096 + w * 512);
        }
    };
    auto stageB = [&](int k0, f16* region) {
#pragma unroll
        for (int q = 0; q < LB; ++q) {
            int r = q * 128 + w * 16 + (l >> 2);
            int c = 8 * ((l & 3) ^ ((r >> 1) & 3));
            gload16(Bb + (size_t)r * K + k0 + c, region + q * 4096 + w * 512);
        }
    };

    f32x4 acc[MW][4] = {};

    // prologue: A_K0(0), B_K0(0), A_K1(0), B_K1(0), A_K0(1), B_K0(1)
    stageA(0, lds);
    stageB(0, lds + 2 * AK);
    stageA(32, lds + AK);
    stageB(32, lds + 2 * AK + BKE);
    stageA(64, lds + SE);
    stageB(64, lds + SE + 2 * AK);

    for (int t = 0; t < NT; ++t) {
        f16* sc_ = lds + (t & 1) * SE;
        f16* sn_ = lds + ((t & 1) ^ 1) * SE;
        f16x8 af[MH], bf[4];

        // ---- phase (kk0, M0): needs A_K0(t), B_K0(t)
        if (t < NT - 1) asm volatile("s_waitcnt vmcnt(%0)" :: "i"(WSTEADY) : "memory");
        else            asm volatile("s_waitcnt vmcnt(%0)" :: "i"(WTAIL) : "memory");
        __builtin_amdgcn_s_barrier();
        __builtin_amdgcn_sched_barrier(0);
        if (t + 1 < NT) stageA((t + 1) * 64 + 32, sn_ + AK);          // A_K1(t+1)
#pragma unroll
        for (int n = 0; n < 4; ++n)
            bf[n] = *reinterpret_cast<const f16x8*>(sc_ + 2 * AK + boff[n]);
#pragma unroll
        for (int m = 0; m < MH; ++m)
            af[m] = *reinterpret_cast<const f16x8*>(sc_ + aoff[m]);
        __builtin_amdgcn_s_setprio(1);
#pragma unroll
        for (int m = 0; m < MH; ++m)
#pragma unroll
            for (int n = 0; n < 4; ++n)
                acc[m][n] = MFMA16(af[m], bf[n], acc[m][n]);
        __builtin_amdgcn_s_setprio(0);

        // ---- phase (kk0, M1)
        __builtin_amdgcn_s_barrier();
        __builtin_amdgcn_sched_barrier(0);
        if (t + 1 < NT) stageB((t + 1) * 64 + 32, sn_ + 2 * AK + BKE); // B_K1(t+1)
#pragma unroll
        for (int m = 0; m < MH; ++m)
            af[m] = *reinterpret_cast<const f16x8*>(sc_ + aoff[MH + m]);
        __builtin_amdgcn_s_setprio(1);
#pragma unroll
        for (int m = 0; m < MH; ++m)
#pragma unroll
            for (int n = 0; n < 4; ++n)
                acc[MH + m][n] = MFMA16(af[m], bf[n], acc[MH + m][n]);
        __builtin_amdgcn_s_setprio(0);

        // ---- phase (kk1, M0): needs A_K1(t), B_K1(t)
        if (t < NT - 1) asm volatile("s_waitcnt vmcnt(%0)" :: "i"(WSTEADY) : "memory");
        else            asm volatile("s_waitcnt vmcnt(0)" ::: "memory");
        __builtin_amdgcn_s_barrier();
        __builtin_amdgcn_sched_barrier(0);
        if (t + 2 < NT) stageA((t + 2) * 64, sc_);                    // A_K0(t+2)
#pragma unroll
        for (int n = 0; n < 4; ++n)
            bf[n] = *reinterpret_cast<const f16x8*>(sc_ + 2 * AK + BKE + boff[n]);
#pragma unroll
        for (int m = 0; m < MH; ++m)
            af[m] = *reinterpret_cast<const f16x8*>(sc_ + AK + aoff[m]);
        __builtin_amdgcn_s_setprio(1);
#pragma unroll
        for (int m = 0; m < MH; ++m)
#pragma unroll
            for (int n = 0; n < 4; ++n)
                acc[m][n] = MFMA16(af[m], bf[n], acc[m][n]);
        __builtin_amdgcn_s_setprio(0);

        // ---- phase (kk1, M1)
        __builtin_amdgcn_s_barrier();
        __builtin_amdgcn_sched_barrier(0);
        if (t + 2 < NT) stageB((t + 2) * 64, sc_ + 2 * AK);           // B_K0(t+2)
#pragma unroll
        for (int m = 0; m < MH; ++m)
            af[m] = *reinterpret_cast<const f16x8*>(sc_ + AK + aoff[MH + m]);
        __builtin_amdgcn_s_setprio(1);
#pragma unroll
        for (int m = 0; m < MH; ++m)
#pragma unroll
            for (int n = 0; n < 4; ++n)
                acc[MH + m][n] = MFMA16(af[m], bf[n], acc[MH + m][n]);
        __builtin_amdgcn_s_setprio(0);
    }

    // epilogue
    const size_t row0 = (size_t)bm * BM + wm * WR;
    const int col0 = bn * BN + wn * 64;
    float bsv[4];
#pragma unroll
    for (int n = 0; n < 4; ++n) bsv[n] = bias[col0 + n * 16 + lrow];
#pragma unroll
    for (int m = 0; m < MW; ++m) {
#pragma unroll
        for (int r = 0; r < 4; ++r) {
            const size_t row = row0 + m * 16 + lq * 4 + r;
            float scl = (EPI >= 1) ? rowsc[row] : 1.0f;
#pragma unroll
            for (int n = 0; n < 4; ++n) {
                float v = acc[m][n][r];
                if (EPI >= 1) v = v * scl;
                v += bsv[n];
                if (EPI >= 1) v = v / (1.f + __expf(-v));
                const size_t idx = row * N + col0 + n * 16 + lrow;
                if (EPI == 2) reinterpret_cast<float*>(Cout)[idx] = v;
                else          reinterpret_cast<f16*>(Cout)[idx] = (f16)v;
            }
        }
    }
}

// ---- windowed GQA attention from combined QKV buffer (row stride 5120) ----
__global__ __launch_bounds__(256) void k_attn(const f16* __restrict__ qkv,
                                              f16* __restrict__ o) {
    __shared__ alignas(16) f16 Ksm[64 * 64];
    __shared__ alignas(16) f16 Vtsm[64 * 64];
    __shared__ alignas(16) f16 Psm[4][64 * 64];
    const int idx = blockIdx.x;
    const int s = idx & 127;
    const int g = (idx >> 7) & 7;
    const int b = idx >> 10;
    const int tid = threadIdx.x;
    const int w = tid >> 6, l = tid & 63;

    const int baseR = s * 32 - 16;
#pragma unroll
    for (int i = 0; i < 2; ++i) {
        const int j = i * 32 + (tid >> 3);
        const int d0 = (tid & 7) * 8;
        const int R = baseR + j;
        f16x8 kvv = {}, vvv = {};
        if (R >= 0 && R < 4096) {
            const f16* rp = qkv + ((size_t)(b * 4096 + R)) * 5120 + 4096 + g * 64 + d0;
            kvv = *reinterpret_cast<const f16x8*>(rp);
            vvv = *reinterpret_cast<const f16x8*>(rp + 512);
        }
        *reinterpret_cast<f16x8*>(&Ksm[j * 64 + d0]) = kvv;
#pragma unroll
        for (int e = 0; e < 8; ++e) Vtsm[(d0 + e) * 64 + j] = vvv[e];
    }

    const int lrow = l & 15, lk = (l >> 4) * 8;
    f16x8 aq[4][2];
#pragma unroll
    for (int m = 0; m < 4; ++m) {
        const int qr = w * 64 + m * 16 + lrow;
        const int h = qr >> 5, qi = qr & 31;
        const f16* qp = qkv + ((size_t)(b * 4096 + s * 32 + qi)) * 5120 + (g * 8 + h) * 64 + lk;
        aq[m][0] = *reinterpret_cast<const f16x8*>(qp);
        aq[m][1] = *reinterpret_cast<const f16x8*>(qp + 32);
    }
    __syncthreads();

    f32x4 acc[4][4] = {};
#pragma unroll
    for (int kk = 0; kk < 2; ++kk) {
        f16x8 bk[4];
#pragma unroll
        for (int n = 0; n < 4; ++n)
            bk[n] = *reinterpret_cast<const f16x8*>(&Ksm[(n * 16 + lrow) * 64 + kk * 32 + lk]);
#pragma unroll
        for (int m = 0; m < 4; ++m)
#pragma unroll
            for (int n = 0; n < 4; ++n)
                acc[m][n] = MFMA16(aq[m][kk], bk[n], acc[m][n]);
    }

    const int nlo = (s == 0) ? 1 : 0;
    const int nhi = (s == 127) ? 3 : 4;
#pragma unroll
    for (int m = 0; m < 4; ++m) {
#pragma unroll
        for (int r = 0; r < 4; ++r) {
            float xv[4];
#pragma unroll
            for (int n = 0; n < 4; ++n) xv[n] = acc[m][n][r] * 0.125f;
            float mx = -1e30f;
            for (int n = nlo; n < nhi; ++n) mx = fmaxf(mx, xv[n]);
#pragma unroll
            for (int off = 8; off > 0; off >>= 1) mx = fmaxf(mx, __shfl_xor(mx, off));
            float pv[4]; float sum = 0.f;
#pragma unroll
            for (int n = 0; n < 4; ++n) {
                float e = (n >= nlo && n < nhi) ? __expf(xv[n] - mx) : 0.f;
                pv[n] = e; sum += e;
            }
#pragma unroll
            for (int off = 8; off > 0; off >>= 1) sum += __shfl_xor(sum, off);
            const float inv = 1.f / sum;
            const int prow = m * 16 + (l >> 4) * 4 + r;
#pragma unroll
            for (int n = 0; n < 4; ++n)
                Psm[w][prow * 64 + n * 16 + lrow] = (f16)(pv[n] * inv);
        }
    }
    __syncthreads();

    f32x4 oacc[4][4] = {};
#pragma unroll
    for (int kk = 0; kk < 2; ++kk) {
        f16x8 ap[4], bv[4];
#pragma unroll
        for (int m = 0; m < 4; ++m)
            ap[m] = *reinterpret_cast<const f16x8*>(&Psm[w][(m * 16 + lrow) * 64 + kk * 32 + lk]);
#pragma unroll
        for (int n = 0; n < 4; ++n)
            bv[n] = *reinterpret_cast<const f16x8*>(&Vtsm[(n * 16 + lrow) * 64 + kk * 32 + lk]);
#pragma unroll
        for (int m = 0; m < 4; ++m)
#pragma unroll
            for (int n = 0; n < 4; ++n)
                oacc[m][n] = MFMA16(ap[m], bv[n], oacc[m][n]);
    }
    const int lr4 = (l >> 4) * 4;
#pragma unroll
    for (int m = 0; m < 4; ++m) {
#pragma unroll
        for (int r = 0; r < 4; ++r) {
            const int qr = w * 64 + m * 16 + lr4 + r;
            const int h = qr >> 5, qi = qr & 31;
            f16* op = o + ((size_t)(b * 4096 + s * 32 + qi)) * 4096 + (g * 8 + h) * 64;
#pragma unroll
            for (int n = 0; n < 4; ++n) op[n * 16 + lrow] = (f16)oacc[m][n][r];
        }
    }
}

extern "C" void kernel_launch(void* const* d_in, const int* in_sizes, int n_in,
                              void* d_out, int out_size, void* d_ws, size_t ws_size,
                              hipStream_t stream) {
    const float* x     = (const float*)d_in[0];
    const float* ng    = (const float*)d_in[1];
    const float* Wq_w  = (const float*)d_in[2];
    const float* Wq_b  = (const float*)d_in[3];
    const float* Wkv_w = (const float*)d_in[4];
    const float* Wkv_b = (const float*)d_in[5];
    const float* g1    = (const float*)d_in[6];
    const float* W1_w  = (const float*)d_in[7];
    const float* W1_b  = (const float*)d_in[8];
    const float* g2    = (const float*)d_in[9];
    const float* W2_w  = (const float*)d_in[10];
    const float* W2_b  = (const float*)d_in[11];
    float* out = (float*)d_out;

    char* p = (char*)d_ws;
    f16* qkv  = (f16*)(p);                 // [8192][5120] 80 MB   [QKV gemm, attn)
    f16* h1   = (f16*)(p);                 // [8192][2048] 32 MB   (over qkv, after attn)
    f16* xn   = (f16*)(p + 83886080);      // [8192][1024] 16 MB   [rmsnorm_x, QKV gemm)
    f16* ob   = (f16*)(p + 83886080);      // [8192][4096] 64 MB   (over xn, written by attn)
    f16* w1   = (f16*)(p + 150994944);     // 16 MB
    f16* w2   = (f16*)(p + 167772160);     // 4 MB
    f16* wqkv = (f16*)(p + 171966464);     // [5120][1024] 10 MB
    float* cb  = (float*)(p + 182452224);  // [5120]
    float* sc1 = (float*)(p + 182472704);  // [8192]
    float* sc2 = (float*)(p + 182505472);  // [8192]

    k_cast<<<4096, 256, 0, stream>>>(Wq_w, wqkv, 4096 * 1024 / 4);
    k_cast<<<1024, 256, 0, stream>>>(Wkv_w, wqkv + 4096 * 1024, 1024 * 1024 / 4);
    k_cast_g<<<8192, 256, 0, stream>>>(W1_w, w1, g1, 4095, 2048 * 4096 / 4);
    k_cast_g<<<2048, 256, 0, stream>>>(W2_w, w2, g2, 2047, 1024 * 2048 / 4);
    k_bias_cat<<<20, 256, 0, stream>>>(Wq_b, Wkv_b, cb);
    k_rmsnorm_x<<<8192, 256, 0, stream>>>(x, ng, xn);

    // QKV: [8192,1024] @ [5120,1024]^T -> [8192,5120]
    k_gemm8p<256, 0, 1><<<640, 512, 0, stream>>>(xn, wqkv, cb, nullptr, qkv, 8192, 5120, 1024);

    k_attn<<<2048, 256, 0, stream>>>(qkv, ob);

    k_rowss<4096><<<8192, 256, 0, stream>>>(ob, sc1);
    // FF1: silu(sc1*(ob @ (g1.W1)^T) + b1) -> h1  (nb=8 -> MODE0)
    k_gemm8p<256, 1, 0><<<256, 512, 0, stream>>>(ob, w1, W1_b, sc1, h1, 8192, 2048, 4096);
    k_rowss<2048><<<8192, 256, 0, stream>>>(h1, sc2);
    // FF2: silu(sc2*(h1 @ (g2.W2)^T) + b2) -> out f32  (nb=8 -> MODE0)
    k_gemm8p<128, 2, 0><<<256, 512, 0, stream>>>(h1, w2, W2_b, sc2, (void*)out, 8192, 1024, 2048);

    (void)in_sizes; (void)n_in; (void)out_size; (void)ws_size;
}

// Round 4
// 394.530 us; speedup vs baseline: 1.3060x; 1.0023x over previous
//
#include <hip/hip_runtime.h>
#include <cstdint>

typedef _Float16 f16;
typedef f16 f16x4 __attribute__((ext_vector_type(4)));
typedef f16 f16x8 __attribute__((ext_vector_type(8)));
typedef float f32x4 __attribute__((ext_vector_type(4)));

#define MFMA16(a, b, c) __builtin_amdgcn_mfma_f32_16x16x32_f16(a, b, c, 0, 0, 0)

static __device__ __forceinline__ void gload16(const void* g, void* l) {
    __builtin_amdgcn_global_load_lds(
        (const __attribute__((address_space(1))) uint32_t*)g,
        (__attribute__((address_space(3))) uint32_t*)l, 16, 0, 0);
}

static __device__ __forceinline__ float blockReduceSum256(float v) {
    __shared__ float red[4];
#pragma unroll
    for (int off = 32; off > 0; off >>= 1) v += __shfl_xor(v, off);
    if ((threadIdx.x & 63) == 0) red[threadIdx.x >> 6] = v;
    __syncthreads();
    return red[0] + red[1] + red[2] + red[3];
}

// ---- rmsnorm(x f32, D=1024) -> f16 ----
__global__ __launch_bounds__(256) void k_rmsnorm_x(const float* __restrict__ x,
                                                   const float* __restrict__ gamma,
                                                   f16* __restrict__ out) {
    size_t row = blockIdx.x;
    const float4 v = reinterpret_cast<const float4*>(x + row * 1024)[threadIdx.x];
    float ss = v.x * v.x + v.y * v.y + v.z * v.z + v.w * v.w;
    ss = blockReduceSum256(ss);
    float sc = 32.0f / fmaxf(sqrtf(ss), 1e-12f);
    const float4 g = reinterpret_cast<const float4*>(gamma)[threadIdx.x];
    f16x4 o;
    o[0] = (f16)(v.x * sc * g.x); o[1] = (f16)(v.y * sc * g.y);
    o[2] = (f16)(v.z * sc * g.z); o[3] = (f16)(v.w * sc * g.w);
    *reinterpret_cast<f16x4*>(out + row * 1024 + threadIdx.x * 4) = o;
}

// ---- per-row scale: sc[row] = sqrt(D)/max(||row||,1e-12) ----
template <int D>
__global__ __launch_bounds__(256) void k_rowss(const f16* __restrict__ in,
                                               float* __restrict__ sc) {
    constexpr int PER = D / 256;
    size_t row = blockIdx.x;
    const f16* ir = in + row * D;
    int c0 = threadIdx.x * PER;
    float ss = 0.f;
#pragma unroll
    for (int i = 0; i < PER; i += 8) {
        f16x8 h = *reinterpret_cast<const f16x8*>(ir + c0 + i);
#pragma unroll
        for (int e = 0; e < 8; ++e) { float f = (float)h[e]; ss += f * f; }
    }
    ss = blockReduceSum256(ss);
    if (threadIdx.x == 0)
        sc[row] = sqrtf((float)D) / fmaxf(sqrtf(ss), 1e-12f);
}

// ---- f32 -> f16 cast ----
__global__ __launch_bounds__(256) void k_cast(const float* __restrict__ in,
                                              f16* __restrict__ out, int n4) {
    int i = blockIdx.x * 256 + threadIdx.x;
    if (i >= n4) return;
    float4 v = reinterpret_cast<const float4*>(in)[i];
    f16x4 o; o[0] = (f16)v.x; o[1] = (f16)v.y; o[2] = (f16)v.z; o[3] = (f16)v.w;
    *reinterpret_cast<f16x4*>(out + (size_t)i * 4) = o;
}

// ---- f32 -> f16 cast with per-column gamma fold (K = kmask+1, pow2) ----
__global__ __launch_bounds__(256) void k_cast_g(const float* __restrict__ in,
                                                f16* __restrict__ out,
                                                const float* __restrict__ gamma,
                                                int kmask, int n4) {
    int i = blockIdx.x * 256 + threadIdx.x;
    if (i >= n4) return;
    float4 v = reinterpret_cast<const float4*>(in)[i];
    int e0 = (i * 4) & kmask;
    f16x4 o;
    o[0] = (f16)(v.x * gamma[e0]); o[1] = (f16)(v.y * gamma[e0 + 1]);
    o[2] = (f16)(v.z * gamma[e0 + 2]); o[3] = (f16)(v.w * gamma[e0 + 3]);
    *reinterpret_cast<f16x4*>(out + (size_t)i * 4) = o;
}

// ---- bias concat ----
__global__ __launch_bounds__(256) void k_bias_cat(const float* __restrict__ a,
                                                  const float* __restrict__ b,
                                                  float* __restrict__ o) {
    int i = blockIdx.x * 256 + threadIdx.x;
    o[i] = (i < 4096) ? a[i] : b[i - 4096];
}

// ==== 4-phase pipelined GEMM with pre-barrier fragment prefetch ====
// C[M,N] = (rowsc?) A[M,K]@Bt[N,K]^T + bias ; EPI 0 f16 / 1 silu f16 / 2 silu f32
// BM=256, BK=64, 512 thr (8 waves). 2 LDS slots x {A_K0,A_K1,B_K0,B_K1}.
// Each phase: BAR -> MFMA (frags preloaded) -> stage -> [vmcnt+BAR] -> ds_read
// next phase's frags -> sched_barrier. Reads overlap prior phase's MFMA drain.
template <int BN, int EPI, int MODE>
__global__ __launch_bounds__(512, 2) void k_gemm8p(const f16* __restrict__ A,
                                                   const f16* __restrict__ Bt,
                                                   const float* __restrict__ bias,
                                                   const float* __restrict__ rowsc,
                                                   void* __restrict__ Cout,
                                                   int M, int N, int K) {
    constexpr int BM = 256;
    constexpr int WN = BN / 64, WM = 8 / WN, WR = BM / WM;
    constexpr int MW = WR / 16, MH = MW / 2;
    constexpr int LA = 2, LB = BN / 128;
    constexpr int WFULL = 2 * (LA + LB), WHALF = LA + LB;
    constexpr int AK = BM * 32;
    constexpr int BKE = BN * 32;
    constexpr int SE = 2 * AK + 2 * BKE;

    __shared__ alignas(16) f16 lds[2 * SE];

    const int nb = N / BN;
    int bn, bm;
    if (MODE == 0) { bn = blockIdx.x & 7; bm = blockIdx.x >> 3; }
    else           { bn = blockIdx.x % nb; bm = blockIdx.x / nb; }

    const int tid = threadIdx.x, w = tid >> 6, l = tid & 63;
    const int wm = w / WN, wn = w % WN;
    const int lrow = l & 15, lq = l >> 4;
    const int g = (lrow >> 1) & 3;

    const f16* Ab = A + (size_t)bm * BM * K;
    const f16* Bb = Bt + (size_t)bn * BN * K;
    const int NT = K >> 6;

    int aoff[MW], boff[4];
#pragma unroll
    for (int m = 0; m < MW; ++m)
        aoff[m] = (wm * WR + m * 16 + lrow) * 32 + 8 * (lq ^ g);
#pragma unroll
    for (int n = 0; n < 4; ++n)
        boff[n] = (wn * 64 + n * 16 + lrow) * 32 + 8 * (lq ^ g);

    auto stageA = [&](int k0, f16* region) {
#pragma unroll
        for (int q = 0; q < LA; ++q) {
            int r = q * 128 + w * 16 + (l >> 2);
            int c = 8 * ((l & 3) ^ ((r >> 1) & 3));
            gload16(Ab + (size_t)r * K + k0 + c, region + q * 4096 + w * 512);
        }
    };
    auto stageB = [&](int k0, f16* region) {
#pragma unroll
        for (int q = 0; q < LB; ++q) {
            int r = q * 128 + w * 16 + (l >> 2);
            int c = 8 * ((l & 3) ^ ((r >> 1) & 3));
            gload16(Bb + (size_t)r * K + k0 + c, region + q * 4096 + w * 512);
        }
    };
    // half h of A frags from LDS base (kk-region already applied by caller)
    auto rdA = [&](f16x8* d, const f16* base, int h) {
#pragma unroll
        for (int m = 0; m < MH; ++m)
            d[m] = *reinterpret_cast<const f16x8*>(base + aoff[h * MH + m]);
    };
    auto rdB = [&](f16x8* d, const f16* base) {
#pragma unroll
        for (int n = 0; n < 4; ++n)
            d[n] = *reinterpret_cast<const f16x8*>(base + boff[n]);
    };

    f32x4 acc[MW][4] = {};
    f16x8 afA[MH], afB[MH], bfA[4], bfB[4];

    // prologue: stage A0(0),B0(0),A1(0),B1(0),A0(1),B0(1); wait first chunk; preload
    stageA(0, lds);
    stageB(0, lds + 2 * AK);
    stageA(32, lds + AK);
    stageB(32, lds + 2 * AK + BKE);
    stageA(64, lds + SE);
    stageB(64, lds + SE + 2 * AK);
    asm volatile("s_waitcnt vmcnt(%0)" :: "i"(WFULL) : "memory");
    __builtin_amdgcn_s_barrier();
    rdA(afA, lds, 0);
    rdB(bfA, lds + 2 * AK);
    __builtin_amdgcn_sched_barrier(0);

    for (int t = 0; t < NT; ++t) {
        f16* sc_ = lds + (t & 1) * SE;
        f16* sn_ = lds + ((t & 1) ^ 1) * SE;

        // ---- P0: MFMA(M0, kk0) ; prefetch af1_K0
        __builtin_amdgcn_s_barrier();
        __builtin_amdgcn_s_setprio(1);
#pragma unroll
        for (int m = 0; m < MH; ++m)
#pragma unroll
            for (int n = 0; n < 4; ++n)
                acc[m][n] = MFMA16(afA[m], bfA[n], acc[m][n]);
        __builtin_amdgcn_s_setprio(0);
        if (t + 1 < NT) stageA((t + 1) * 64 + 32, sn_ + AK);          // A1(t+1)
        rdA(afB, sc_, 1);                                             // af1_K0
        __builtin_amdgcn_sched_barrier(0);

        // ---- P1: MFMA(M1, kk0) ; vmcnt+BAR ; prefetch af0_K1, bf_K1
        __builtin_amdgcn_s_barrier();
        __builtin_amdgcn_s_setprio(1);
#pragma unroll
        for (int m = 0; m < MH; ++m)
#pragma unroll
            for (int n = 0; n < 4; ++n)
                acc[MH + m][n] = MFMA16(afB[m], bfA[n], acc[MH + m][n]);
        __builtin_amdgcn_s_setprio(0);
        if (t + 1 < NT) stageB((t + 1) * 64 + 32, sn_ + 2 * AK + BKE); // B1(t+1)
        if (t < NT - 1) asm volatile("s_waitcnt vmcnt(%0)" :: "i"(WFULL) : "memory");
        else            asm volatile("s_waitcnt vmcnt(0)" ::: "memory");
        __builtin_amdgcn_s_barrier();
        rdA(afA, sc_ + AK, 0);                                        // af0_K1
        rdB(bfB, sc_ + 2 * AK + BKE);                                 // bf_K1
        __builtin_amdgcn_sched_barrier(0);

        // ---- P2: MFMA(M0, kk1) ; prefetch af1_K1
        __builtin_amdgcn_s_barrier();
        __builtin_amdgcn_s_setprio(1);
#pragma unroll
        for (int m = 0; m < MH; ++m)
#pragma unroll
            for (int n = 0; n < 4; ++n)
                acc[m][n] = MFMA16(afA[m], bfB[n], acc[m][n]);
        __builtin_amdgcn_s_setprio(0);
        if (t + 2 < NT) stageA((t + 2) * 64, sc_);                    // A0(t+2)
        rdA(afB, sc_ + AK, 1);                                        // af1_K1
        __builtin_amdgcn_sched_barrier(0);

        // ---- P3: MFMA(M1, kk1) ; vmcnt+BAR ; prefetch next tile's K0 frags
        __builtin_amdgcn_s_barrier();
        __builtin_amdgcn_s_setprio(1);
#pragma unroll
        for (int m = 0; m < MH; ++m)
#pragma unroll
            for (int n = 0; n < 4; ++n)
                acc[MH + m][n] = MFMA16(afB[m], bfB[n], acc[MH + m][n]);
        __builtin_amdgcn_s_setprio(0);
        if (t + 2 < NT) stageB((t + 2) * 64, sc_ + 2 * AK);           // B0(t+2)
        if (t + 1 < NT) {
            if (t < NT - 2) asm volatile("s_waitcnt vmcnt(%0)" :: "i"(WFULL) : "memory");
            else            asm volatile("s_waitcnt vmcnt(%0)" :: "i"(WHALF) : "memory");
            __builtin_amdgcn_s_barrier();
            rdA(afA, sn_, 0);                                         // af0_K0(t+1)
            rdB(bfA, sn_ + 2 * AK);                                   // bf_K0(t+1)
            __builtin_amdgcn_sched_barrier(0);
        }
    }

    // epilogue
    const size_t row0 = (size_t)bm * BM + wm * WR;
    const int col0 = bn * BN + wn * 64;
    float bsv[4];
#pragma unroll
    for (int n = 0; n < 4; ++n) bsv[n] = bias[col0 + n * 16 + lrow];
#pragma unroll
    for (int m = 0; m < MW; ++m) {
#pragma unroll
        for (int r = 0; r < 4; ++r) {
            const size_t row = row0 + m * 16 + lq * 4 + r;
            float scl = (EPI >= 1) ? rowsc[row] : 1.0f;
#pragma unroll
            for (int n = 0; n < 4; ++n) {
                float v = acc[m][n][r];
                if (EPI >= 1) v = v * scl;
                v += bsv[n];
                if (EPI >= 1) v = v / (1.f + __expf(-v));
                const size_t idx = row * N + col0 + n * 16 + lrow;
                if (EPI == 2) reinterpret_cast<float*>(Cout)[idx] = v;
                else          reinterpret_cast<f16*>(Cout)[idx] = (f16)v;
            }
        }
    }
}

// ---- windowed GQA attention from combined QKV buffer (row stride 5120) ----
__global__ __launch_bounds__(256) void k_attn(const f16* __restrict__ qkv,
                                              f16* __restrict__ o) {
    __shared__ alignas(16) f16 Ksm[64 * 64];
    __shared__ alignas(16) f16 Vtsm[64 * 64];
    __shared__ alignas(16) f16 Psm[4][64 * 64];
    const int idx = blockIdx.x;
    const int s = idx & 127;
    const int g = (idx >> 7) & 7;
    const int b = idx >> 10;
    const int tid = threadIdx.x;
    const int w = tid >> 6, l = tid & 63;

    const int baseR = s * 32 - 16;
#pragma unroll
    for (int i = 0; i < 2; ++i) {
        const int j = i * 32 + (tid >> 3);
        const int d0 = (tid & 7) * 8;
        const int R = baseR + j;
        f16x8 kvv = {}, vvv = {};
        if (R >= 0 && R < 4096) {
            const f16* rp = qkv + ((size_t)(b * 4096 + R)) * 5120 + 4096 + g * 64 + d0;
            kvv = *reinterpret_cast<const f16x8*>(rp);
            vvv = *reinterpret_cast<const f16x8*>(rp + 512);
        }
        *reinterpret_cast<f16x8*>(&Ksm[j * 64 + d0]) = kvv;
#pragma unroll
        for (int e = 0; e < 8; ++e) Vtsm[(d0 + e) * 64 + j] = vvv[e];
    }

    const int lrow = l & 15, lk = (l >> 4) * 8;
    f16x8 aq[4][2];
#pragma unroll
    for (int m = 0; m < 4; ++m) {
        const int qr = w * 64 + m * 16 + lrow;
        const int h = qr >> 5, qi = qr & 31;
        const f16* qp = qkv + ((size_t)(b * 4096 + s * 32 + qi)) * 5120 + (g * 8 + h) * 64 + lk;
        aq[m][0] = *reinterpret_cast<const f16x8*>(qp);
        aq[m][1] = *reinterpret_cast<const f16x8*>(qp + 32);
    }
    __syncthreads();

    f32x4 acc[4][4] = {};
#pragma unroll
    for (int kk = 0; kk < 2; ++kk) {
        f16x8 bk[4];
#pragma unroll
        for (int n = 0; n < 4; ++n)
            bk[n] = *reinterpret_cast<const f16x8*>(&Ksm[(n * 16 + lrow) * 64 + kk * 32 + lk]);
#pragma unroll
        for (int m = 0; m < 4; ++m)
#pragma unroll
            for (int n = 0; n < 4; ++n)
                acc[m][n] = MFMA16(aq[m][kk], bk[n], acc[m][n]);
    }

    const int nlo = (s == 0) ? 1 : 0;
    const int nhi = (s == 127) ? 3 : 4;
#pragma unroll
    for (int m = 0; m < 4; ++m) {
#pragma unroll
        for (int r = 0; r < 4; ++r) {
            float xv[4];
#pragma unroll
            for (int n = 0; n < 4; ++n) xv[n] = acc[m][n][r] * 0.125f;
            float mx = -1e30f;
            for (int n = nlo; n < nhi; ++n) mx = fmaxf(mx, xv[n]);
#pragma unroll
            for (int off = 8; off > 0; off >>= 1) mx = fmaxf(mx, __shfl_xor(mx, off));
            float pv[4]; float sum = 0.f;
#pragma unroll
            for (int n = 0; n < 4; ++n) {
                float e = (n >= nlo && n < nhi) ? __expf(xv[n] - mx) : 0.f;
                pv[n] = e; sum += e;
            }
#pragma unroll
            for (int off = 8; off > 0; off >>= 1) sum += __shfl_xor(sum, off);
            const float inv = 1.f / sum;
            const int prow = m * 16 + (l >> 4) * 4 + r;
#pragma unroll
            for (int n = 0; n < 4; ++n)
                Psm[w][prow * 64 + n * 16 + lrow] = (f16)(pv[n] * inv);
        }
    }
    __syncthreads();

    f32x4 oacc[4][4] = {};
#pragma unroll
    for (int kk = 0; kk < 2; ++kk) {
        f16x8 ap[4], bv[4];
#pragma unroll
        for (int m = 0; m < 4; ++m)
            ap[m] = *reinterpret_cast<const f16x8*>(&Psm[w][(m * 16 + lrow) * 64 + kk * 32 + lk]);
#pragma unroll
        for (int n = 0; n < 4; ++n)
            bv[n] = *reinterpret_cast<const f16x8*>(&Vtsm[(n * 16 + lrow) * 64 + kk * 32 + lk]);
#pragma unroll
        for (int m = 0; m < 4; ++m)
#pragma unroll
            for (int n = 0; n < 4; ++n)
                oacc[m][n] = MFMA16(ap[m], bv[n], oacc[m][n]);
    }
    const int lr4 = (l >> 4) * 4;
#pragma unroll
    for (int m = 0; m < 4; ++m) {
#pragma unroll
        for (int r = 0; r < 4; ++r) {
            const int qr = w * 64 + m * 16 + lr4 + r;
            const int h = qr >> 5, qi = qr & 31;
            f16* op = o + ((size_t)(b * 4096 + s * 32 + qi)) * 4096 + (g * 8 + h) * 64;
#pragma unroll
            for (int n = 0; n < 4; ++n) op[n * 16 + lrow] = (f16)oacc[m][n][r];
        }
    }
}

extern "C" void kernel_launch(void* const* d_in, const int* in_sizes, int n_in,
                              void* d_out, int out_size, void* d_ws, size_t ws_size,
                              hipStream_t stream) {
    const float* x     = (const float*)d_in[0];
    const float* ng    = (const float*)d_in[1];
    const float* Wq_w  = (const float*)d_in[2];
    const float* Wq_b  = (const float*)d_in[3];
    const float* Wkv_w = (const float*)d_in[4];
    const float* Wkv_b = (const float*)d_in[5];
    const float* g1    = (const float*)d_in[6];
    const float* W1_w  = (const float*)d_in[7];
    const float* W1_b  = (const float*)d_in[8];
    const float* g2    = (const float*)d_in[9];
    const float* W2_w  = (const float*)d_in[10];
    const float* W2_b  = (const float*)d_in[11];
    float* out = (float*)d_out;

    char* p = (char*)d_ws;
    f16* qkv  = (f16*)(p);                 // [8192][5120] 80 MB
    f16* h1   = (f16*)(p);                 // [8192][2048] (over qkv, after attn)
    f16* xn   = (f16*)(p + 83886080);      // [8192][1024]
    f16* ob   = (f16*)(p + 83886080);      // [8192][4096] (over xn, written by attn)
    f16* w1   = (f16*)(p + 150994944);     // 16 MB
    f16* w2   = (f16*)(p + 167772160);     // 4 MB
    f16* wqkv = (f16*)(p + 171966464);     // [5120][1024] 10 MB
    float* cb  = (float*)(p + 182452224);
    float* sc1 = (float*)(p + 182472704);
    float* sc2 = (float*)(p + 182505472);

    k_cast<<<4096, 256, 0, stream>>>(Wq_w, wqkv, 4096 * 1024 / 4);
    k_cast<<<1024, 256, 0, stream>>>(Wkv_w, wqkv + 4096 * 1024, 1024 * 1024 / 4);
    k_cast_g<<<8192, 256, 0, stream>>>(W1_w, w1, g1, 4095, 2048 * 4096 / 4);
    k_cast_g<<<2048, 256, 0, stream>>>(W2_w, w2, g2, 2047, 1024 * 2048 / 4);
    k_bias_cat<<<20, 256, 0, stream>>>(Wq_b, Wkv_b, cb);
    k_rmsnorm_x<<<8192, 256, 0, stream>>>(x, ng, xn);

    // QKV: [8192,1024] @ [5120,1024]^T -> [8192,5120]
    k_gemm8p<256, 0, 1><<<640, 512, 0, stream>>>(xn, wqkv, cb, nullptr, qkv, 8192, 5120, 1024);

    k_attn<<<2048, 256, 0, stream>>>(qkv, ob);

    k_rowss<4096><<<8192, 256, 0, stream>>>(ob, sc1);
    k_gemm8p<256, 1, 0><<<256, 512, 0, stream>>>(ob, w1, W1_b, sc1, h1, 8192, 2048, 4096);
    k_rowss<2048><<<8192, 256, 0, stream>>>(h1, sc2);
    k_gemm8p<128, 2, 0><<<256, 512, 0, stream>>>(h1, w2, W2_b, sc2, (void*)out, 8192, 1024, 2048);

    (void)in_sizes; (void)n_in; (void)out_size; (void)ws_size;
}

// Round 5
// 371.901 us; speedup vs baseline: 1.3855x; 1.0608x over previous
//
#include <hip/hip_runtime.h>
#include <cstdint>

typedef _Float16 f16;
typedef f16 f16x4 __attribute__((ext_vector_type(4)));
typedef f16 f16x8 __attribute__((ext_vector_type(8)));
typedef float f32x4 __attribute__((ext_vector_type(4)));

#define MFMA16(a, b, c) __builtin_amdgcn_mfma_f32_16x16x32_f16(a, b, c, 0, 0, 0)

static __device__ __forceinline__ void gload16(const void* g, void* l) {
    __builtin_amdgcn_global_load_lds(
        (const __attribute__((address_space(1))) uint32_t*)g,
        (__attribute__((address_space(3))) uint32_t*)l, 16, 0, 0);
}

// SGB-directed phase layout: NV VMEM (stage), then ND groups of {NM/ND MFMA, 1 DS_READ}
template <int NM, int ND, int NV>
static __device__ __forceinline__ void sgb_phase() {
    if (NV > 0) __builtin_amdgcn_sched_group_barrier(0x10, NV, 0);
    constexpr int PER = NM / ND;
#pragma unroll
    for (int i = 0; i < ND; ++i) {
        __builtin_amdgcn_sched_group_barrier(0x8, PER, 0);
        __builtin_amdgcn_sched_group_barrier(0x100, 1, 0);
    }
    if (NM - PER * ND > 0)
        __builtin_amdgcn_sched_group_barrier(0x8, NM - PER * ND, 0);
}

static __device__ __forceinline__ float blockReduceSum256(float v) {
    __shared__ float red[4];
#pragma unroll
    for (int off = 32; off > 0; off >>= 1) v += __shfl_xor(v, off);
    if ((threadIdx.x & 63) == 0) red[threadIdx.x >> 6] = v;
    __syncthreads();
    return red[0] + red[1] + red[2] + red[3];
}

// ---- rmsnorm(x f32, D=1024) -> f16 ----
__global__ __launch_bounds__(256) void k_rmsnorm_x(const float* __restrict__ x,
                                                   const float* __restrict__ gamma,
                                                   f16* __restrict__ out) {
    size_t row = blockIdx.x;
    const float4 v = reinterpret_cast<const float4*>(x + row * 1024)[threadIdx.x];
    float ss = v.x * v.x + v.y * v.y + v.z * v.z + v.w * v.w;
    ss = blockReduceSum256(ss);
    float sc = 32.0f / fmaxf(sqrtf(ss), 1e-12f);
    const float4 g = reinterpret_cast<const float4*>(gamma)[threadIdx.x];
    f16x4 o;
    o[0] = (f16)(v.x * sc * g.x); o[1] = (f16)(v.y * sc * g.y);
    o[2] = (f16)(v.z * sc * g.z); o[3] = (f16)(v.w * sc * g.w);
    *reinterpret_cast<f16x4*>(out + row * 1024 + threadIdx.x * 4) = o;
}

// ---- per-row scale: sc[row] = sqrt(D)/max(||row||,1e-12) ----
template <int D>
__global__ __launch_bounds__(256) void k_rowss(const f16* __restrict__ in,
                                               float* __restrict__ sc) {
    constexpr int PER = D / 256;
    size_t row = blockIdx.x;
    const f16* ir = in + row * D;
    int c0 = threadIdx.x * PER;
    float ss = 0.f;
#pragma unroll
    for (int i = 0; i < PER; i += 8) {
        f16x8 h = *reinterpret_cast<const f16x8*>(ir + c0 + i);
#pragma unroll
        for (int e = 0; e < 8; ++e) { float f = (float)h[e]; ss += f * f; }
    }
    ss = blockReduceSum256(ss);
    if (threadIdx.x == 0)
        sc[row] = sqrtf((float)D) / fmaxf(sqrtf(ss), 1e-12f);
}

// ---- f32 -> f16 cast ----
__global__ __launch_bounds__(256) void k_cast(const float* __restrict__ in,
                                              f16* __restrict__ out, int n4) {
    int i = blockIdx.x * 256 + threadIdx.x;
    if (i >= n4) return;
    float4 v = reinterpret_cast<const float4*>(in)[i];
    f16x4 o; o[0] = (f16)v.x; o[1] = (f16)v.y; o[2] = (f16)v.z; o[3] = (f16)v.w;
    *reinterpret_cast<f16x4*>(out + (size_t)i * 4) = o;
}

// ---- f32 -> f16 cast with per-column gamma fold (K = kmask+1, pow2) ----
__global__ __launch_bounds__(256) void k_cast_g(const float* __restrict__ in,
                                                f16* __restrict__ out,
                                                const float* __restrict__ gamma,
                                                int kmask, int n4) {
    int i = blockIdx.x * 256 + threadIdx.x;
    if (i >= n4) return;
    float4 v = reinterpret_cast<const float4*>(in)[i];
    int e0 = (i * 4) & kmask;
    f16x4 o;
    o[0] = (f16)(v.x * gamma[e0]); o[1] = (f16)(v.y * gamma[e0 + 1]);
    o[2] = (f16)(v.z * gamma[e0 + 2]); o[3] = (f16)(v.w * gamma[e0 + 3]);
    *reinterpret_cast<f16x4*>(out + (size_t)i * 4) = o;
}

// ---- bias concat ----
__global__ __launch_bounds__(256) void k_bias_cat(const float* __restrict__ a,
                                                  const float* __restrict__ b,
                                                  float* __restrict__ o) {
    int i = blockIdx.x * 256 + threadIdx.x;
    o[i] = (i < 4096) ? a[i] : b[i - 4096];
}

// ==== 4-phase SGB-interleaved GEMM: C = A[M,K]@Bt[N,K]^T (+rowsc, bias, silu) ====
template <int BN, int EPI, int MODE>
__global__ __launch_bounds__(512, 2) void k_gemm8p(const f16* __restrict__ A,
                                                   const f16* __restrict__ Bt,
                                                   const float* __restrict__ bias,
                                                   const float* __restrict__ rowsc,
                                                   void* __restrict__ Cout,
                                                   int M, int N, int K) {
    constexpr int BM = 256;
    constexpr int WN = BN / 64, WM = 8 / WN, WR = BM / WM;
    constexpr int MW = WR / 16, MH = MW / 2;
    constexpr int LA = 2, LB = BN / 128;
    constexpr int VS = 2 * LA + LB;          // steady vmcnt
    constexpr int AK = BM * 32;              // elems per A K-half region
    constexpr int BKE = BN * 32;
    constexpr int SE = 2 * AK + 2 * BKE;

    __shared__ alignas(16) f16 lds[2 * SE];

    const int nb = N / BN;
    int bn, bm;
    if (MODE == 0) { bn = blockIdx.x & 7; bm = blockIdx.x >> 3; }
    else           { bn = blockIdx.x % nb; bm = blockIdx.x / nb; }

    const int tid = threadIdx.x, w = tid >> 6, l = tid & 63;
    const int wm = w / WN, wn = w % WN;
    const int lrow = l & 15, lq = l >> 4;
    const int g = (lrow >> 1) & 3;

    const f16* Ab = A + (size_t)bm * BM * K;
    const f16* Bb = Bt + (size_t)bn * BN * K;
    const int NT = K >> 6;

    int aoff[MW], boff[4];
#pragma unroll
    for (int m = 0; m < MW; ++m)
        aoff[m] = (wm * WR + m * 16 + lrow) * 32 + 8 * (lq ^ g);
#pragma unroll
    for (int n = 0; n < 4; ++n)
        boff[n] = (wn * 64 + n * 16 + lrow) * 32 + 8 * (lq ^ g);

    auto stageA = [&](int k0, f16* region) {
#pragma unroll
        for (int q = 0; q < LA; ++q) {
            int r = q * 128 + w * 16 + (l >> 2);
            int c = 8 * ((l & 3) ^ ((r >> 1) & 3));
            gload16(Ab + (size_t)r * K + k0 + c, region + q * 4096 + w * 512);
        }
    };
    auto stageB = [&](int k0, f16* region) {
#pragma unroll
        for (int q = 0; q < LB; ++q) {
            int r = q * 128 + w * 16 + (l >> 2);
            int c = 8 * ((l & 3) ^ ((r >> 1) & 3));
            gload16(Bb + (size_t)r * K + k0 + c, region + q * 4096 + w * 512);
        }
    };
    auto rdA = [&](f16x8 (&d)[MH], const f16* base, int h) {
#pragma unroll
        for (int m = 0; m < MH; ++m)
            d[m] = *reinterpret_cast<const f16x8*>(base + aoff[h * MH + m]);
    };
    auto rdB = [&](f16x8 (&d)[4], const f16* base) {
#pragma unroll
        for (int n = 0; n < 4; ++n)
            d[n] = *reinterpret_cast<const f16x8*>(base + boff[n]);
    };

    f32x4 acc[MW][4] = {};
    f16x8 afA[MH], afB[MH], bfA[4], bfB[4];

    auto mfmaLo = [&](f16x8 (&af)[MH], f16x8 (&bf)[4]) {
#pragma unroll
        for (int m = 0; m < MH; ++m)
#pragma unroll
            for (int n = 0; n < 4; ++n)
                acc[m][n] = MFMA16(af[m], bf[n], acc[m][n]);
    };
    auto mfmaHi = [&](f16x8 (&af)[MH], f16x8 (&bf)[4]) {
#pragma unroll
        for (int m = 0; m < MH; ++m)
#pragma unroll
            for (int n = 0; n < 4; ++n)
                acc[MH + m][n] = MFMA16(af[m], bf[n], acc[MH + m][n]);
    };

    // prologue: stage kk0(0), kk1(0), kk0(1); wait kk0(0); preload frags
    stageA(0, lds);             stageB(0, lds + 2 * AK);
    stageA(32, lds + AK);       stageB(32, lds + 2 * AK + BKE);
    stageA(64, lds + SE);       stageB(64, lds + SE + 2 * AK);
    asm volatile("s_waitcnt vmcnt(%0)" :: "i"(2 * (LA + LB)) : "memory");
    __builtin_amdgcn_s_barrier();
    rdA(afA, lds, 0);
    rdB(bfA, lds + 2 * AK);

    const int NTm2 = NT - 2;
    for (int t = 0; t < NTm2; ++t) {
        f16* s0 = lds + (t & 1) * SE;
        f16* s1 = lds + ((t & 1) ^ 1) * SE;
        const int kn1 = (t + 1) << 6;
        const int kn2 = (t + 2) << 6;
        // ph0: MFMA(M0,kk0) | read af1_kk0 | stage A1(t+1)
        __builtin_amdgcn_s_barrier();
        stageA(kn1 + 32, s1 + AK);
        rdA(afB, s0, 1);
        mfmaLo(afA, bfA);
        sgb_phase<MH * 4, MH, LA>();
        // ph1: MFMA(M1,kk0) | read af0_kk1 + bf_kk1 | stage B1(t+1)
        asm volatile("s_waitcnt vmcnt(%0)" :: "i"(VS) : "memory");
        __builtin_amdgcn_s_barrier();
        stageB(kn1 + 32, s1 + 2 * AK + BKE);
        rdA(afA, s0 + AK, 0);
        rdB(bfB, s0 + 2 * AK + BKE);
        mfmaHi(afB, bfA);
        sgb_phase<MH * 4, MH + 4, LB>();
        // ph2: MFMA(M0,kk1) | read af1_kk1 | stage A0(t+2)
        __builtin_amdgcn_s_barrier();
        stageA(kn2, s0);
        rdA(afB, s0 + AK, 1);
        mfmaLo(afA, bfB);
        sgb_phase<MH * 4, MH, LA>();
        // ph3: MFMA(M1,kk1) | read af0_kk0(t+1) + bf_kk0(t+1) | stage B0(t+2)
        asm volatile("s_waitcnt vmcnt(%0)" :: "i"(VS) : "memory");
        __builtin_amdgcn_s_barrier();
        stageB(kn2, s0 + 2 * AK);
        rdA(afA, s1, 0);
        rdB(bfA, s1 + 2 * AK);
        mfmaHi(afB, bfB);
        sgb_phase<MH * 4, MH + 4, LB>();
    }
    // t = NT-2 (no t+2 stages; tail waits)
    {
        const int t = NTm2;
        f16* s0 = lds + (t & 1) * SE;
        f16* s1 = lds + ((t & 1) ^ 1) * SE;
        const int kn1 = (t + 1) << 6;
        __builtin_amdgcn_s_barrier();
        stageA(kn1 + 32, s1 + AK);
        rdA(afB, s0, 1);
        mfmaLo(afA, bfA);
        sgb_phase<MH * 4, MH, LA>();
        asm volatile("s_waitcnt vmcnt(%0)" :: "i"(VS) : "memory");
        __builtin_amdgcn_s_barrier();
        stageB(kn1 + 32, s1 + 2 * AK + BKE);
        rdA(afA, s0 + AK, 0);
        rdB(bfB, s0 + 2 * AK + BKE);
        mfmaHi(afB, bfA);
        sgb_phase<MH * 4, MH + 4, LB>();
        __builtin_amdgcn_s_barrier();
        rdA(afB, s0 + AK, 1);
        mfmaLo(afA, bfB);
        sgb_phase<MH * 4, MH, 0>();
        asm volatile("s_waitcnt vmcnt(%0)" :: "i"(LA + LB) : "memory");
        __builtin_amdgcn_s_barrier();
        rdA(afA, s1, 0);
        rdB(bfA, s1 + 2 * AK);
        mfmaHi(afB, bfB);
        sgb_phase<MH * 4, MH + 4, 0>();
    }
    // t = NT-1 (no stages, final drain)
    {
        f16* s0 = lds + ((NT - 1) & 1) * SE;
        __builtin_amdgcn_s_barrier();
        rdA(afB, s0, 1);
        mfmaLo(afA, bfA);
        sgb_phase<MH * 4, MH, 0>();
        asm volatile("s_waitcnt vmcnt(0)" ::: "memory");
        __builtin_amdgcn_s_barrier();
        rdA(afA, s0 + AK, 0);
        rdB(bfB, s0 + 2 * AK + BKE);
        mfmaHi(afB, bfA);
        sgb_phase<MH * 4, MH + 4, 0>();
        __builtin_amdgcn_s_barrier();
        rdA(afB, s0 + AK, 1);
        mfmaLo(afA, bfB);
        sgb_phase<MH * 4, MH, 0>();
        mfmaHi(afB, bfB);
    }

    // epilogue
    const size_t row0 = (size_t)bm * BM + wm * WR;
    const int col0 = bn * BN + wn * 64;
    float bsv[4];
#pragma unroll
    for (int n = 0; n < 4; ++n) bsv[n] = bias[col0 + n * 16 + lrow];
#pragma unroll
    for (int m = 0; m < MW; ++m) {
#pragma unroll
        for (int r = 0; r < 4; ++r) {
            const size_t row = row0 + m * 16 + lq * 4 + r;
            float scl = (EPI >= 1) ? rowsc[row] : 1.0f;
#pragma unroll
            for (int n = 0; n < 4; ++n) {
                float v = acc[m][n][r];
                if (EPI >= 1) v = v * scl;
                v += bsv[n];
                if (EPI >= 1) v = v / (1.f + __expf(-v));
                const size_t idx = row * N + col0 + n * 16 + lrow;
                if (EPI == 2) reinterpret_cast<float*>(Cout)[idx] = v;
                else          reinterpret_cast<f16*>(Cout)[idx] = (f16)v;
            }
        }
    }
}

// ---- windowed GQA attention from combined QKV buffer (row stride 5120) ----
__global__ __launch_bounds__(256) void k_attn(const f16* __restrict__ qkv,
                                              f16* __restrict__ o) {
    __shared__ alignas(16) f16 Ksm[64 * 64];
    __shared__ alignas(16) f16 Vtsm[64 * 64];
    __shared__ alignas(16) f16 Psm[4][64 * 64];
    const int idx = blockIdx.x;
    const int s = idx & 127;
    const int g = (idx >> 7) & 7;
    const int b = idx >> 10;
    const int tid = threadIdx.x;
    const int w = tid >> 6, l = tid & 63;

    const int baseR = s * 32 - 16;
#pragma unroll
    for (int i = 0; i < 2; ++i) {
        const int j = i * 32 + (tid >> 3);
        const int d0 = (tid & 7) * 8;
        const int R = baseR + j;
        f16x8 kvv = {}, vvv = {};
        if (R >= 0 && R < 4096) {
            const f16* rp = qkv + ((size_t)(b * 4096 + R)) * 5120 + 4096 + g * 64 + d0;
            kvv = *reinterpret_cast<const f16x8*>(rp);
            vvv = *reinterpret_cast<const f16x8*>(rp + 512);
        }
        *reinterpret_cast<f16x8*>(&Ksm[j * 64 + d0]) = kvv;
#pragma unroll
        for (int e = 0; e < 8; ++e) Vtsm[(d0 + e) * 64 + j] = vvv[e];
    }

    const int lrow = l & 15, lk = (l >> 4) * 8;
    f16x8 aq[4][2];
#pragma unroll
    for (int m = 0; m < 4; ++m) {
        const int qr = w * 64 + m * 16 + lrow;
        const int h = qr >> 5, qi = qr & 31;
        const f16* qp = qkv + ((size_t)(b * 4096 + s * 32 + qi)) * 5120 + (g * 8 + h) * 64 + lk;
        aq[m][0] = *reinterpret_cast<const f16x8*>(qp);
        aq[m][1] = *reinterpret_cast<const f16x8*>(qp + 32);
    }
    __syncthreads();

    f32x4 acc[4][4] = {};
#pragma unroll
    for (int kk = 0; kk < 2; ++kk) {
        f16x8 bk[4];
#pragma unroll
        for (int n = 0; n < 4; ++n)
            bk[n] = *reinterpret_cast<const f16x8*>(&Ksm[(n * 16 + lrow) * 64 + kk * 32 + lk]);
#pragma unroll
        for (int m = 0; m < 4; ++m)
#pragma unroll
            for (int n = 0; n < 4; ++n)
                acc[m][n] = MFMA16(aq[m][kk], bk[n], acc[m][n]);
    }

    const int nlo = (s == 0) ? 1 : 0;
    const int nhi = (s == 127) ? 3 : 4;
#pragma unroll
    for (int m = 0; m < 4; ++m) {
#pragma unroll
        for (int r = 0; r < 4; ++r) {
            float xv[4];
#pragma unroll
            for (int n = 0; n < 4; ++n) xv[n] = acc[m][n][r] * 0.125f;
            float mx = -1e30f;
            for (int n = nlo; n < nhi; ++n) mx = fmaxf(mx, xv[n]);
#pragma unroll
            for (int off = 8; off > 0; off >>= 1) mx = fmaxf(mx, __shfl_xor(mx, off));
            float pv[4]; float sum = 0.f;
#pragma unroll
            for (int n = 0; n < 4; ++n) {
                float e = (n >= nlo && n < nhi) ? __expf(xv[n] - mx) : 0.f;
                pv[n] = e; sum += e;
            }
#pragma unroll
            for (int off = 8; off > 0; off >>= 1) sum += __shfl_xor(sum, off);
            const float inv = 1.f / sum;
            const int prow = m * 16 + (l >> 4) * 4 + r;
#pragma unroll
            for (int n = 0; n < 4; ++n)
                Psm[w][prow * 64 + n * 16 + lrow] = (f16)(pv[n] * inv);
        }
    }
    __syncthreads();

    f32x4 oacc[4][4] = {};
#pragma unroll
    for (int kk = 0; kk < 2; ++kk) {
        f16x8 ap[4], bv[4];
#pragma unroll
        for (int m = 0; m < 4; ++m)
            ap[m] = *reinterpret_cast<const f16x8*>(&Psm[w][(m * 16 + lrow) * 64 + kk * 32 + lk]);
#pragma unroll
        for (int n = 0; n < 4; ++n)
            bv[n] = *reinterpret_cast<const f16x8*>(&Vtsm[(n * 16 + lrow) * 64 + kk * 32 + lk]);
#pragma unroll
        for (int m = 0; m < 4; ++m)
#pragma unroll
            for (int n = 0; n < 4; ++n)
                oacc[m][n] = MFMA16(ap[m], bv[n], oacc[m][n]);
    }
    const int lr4 = (l >> 4) * 4;
#pragma unroll
    for (int m = 0; m < 4; ++m) {
#pragma unroll
        for (int r = 0; r < 4; ++r) {
            const int qr = w * 64 + m * 16 + lr4 + r;
            const int h = qr >> 5, qi = qr & 31;
            f16* op = o + ((size_t)(b * 4096 + s * 32 + qi)) * 4096 + (g * 8 + h) * 64;
#pragma unroll
            for (int n = 0; n < 4; ++n) op[n * 16 + lrow] = (f16)oacc[m][n][r];
        }
    }
}

extern "C" void kernel_launch(void* const* d_in, const int* in_sizes, int n_in,
                              void* d_out, int out_size, void* d_ws, size_t ws_size,
                              hipStream_t stream) {
    const float* x     = (const float*)d_in[0];
    const float* ng    = (const float*)d_in[1];
    const float* Wq_w  = (const float*)d_in[2];
    const float* Wq_b  = (const float*)d_in[3];
    const float* Wkv_w = (const float*)d_in[4];
    const float* Wkv_b = (const float*)d_in[5];
    const float* g1    = (const float*)d_in[6];
    const float* W1_w  = (const float*)d_in[7];
    const float* W1_b  = (const float*)d_in[8];
    const float* g2    = (const float*)d_in[9];
    const float* W2_w  = (const float*)d_in[10];
    const float* W2_b  = (const float*)d_in[11];
    float* out = (float*)d_out;

    char* p = (char*)d_ws;
    f16* qkv  = (f16*)(p);                 // [8192][5120] 80 MB
    f16* h1   = (f16*)(p);                 // [8192][2048] (over qkv, after attn)
    f16* xn   = (f16*)(p + 83886080);      // [8192][1024]
    f16* ob   = (f16*)(p + 83886080);      // [8192][4096] (over xn, written by attn)
    f16* w1   = (f16*)(p + 150994944);     // 16 MB
    f16* w2   = (f16*)(p + 167772160);     // 4 MB
    f16* wqkv = (f16*)(p + 171966464);     // [5120][1024] 10 MB
    float* cb  = (float*)(p + 182452224);
    float* sc1 = (float*)(p + 182472704);
    float* sc2 = (float*)(p + 182505472);

    k_cast<<<4096, 256, 0, stream>>>(Wq_w, wqkv, 4096 * 1024 / 4);
    k_cast<<<1024, 256, 0, stream>>>(Wkv_w, wqkv + 4096 * 1024, 1024 * 1024 / 4);
    k_cast_g<<<8192, 256, 0, stream>>>(W1_w, w1, g1, 4095, 2048 * 4096 / 4);
    k_cast_g<<<2048, 256, 0, stream>>>(W2_w, w2, g2, 2047, 1024 * 2048 / 4);
    k_bias_cat<<<20, 256, 0, stream>>>(Wq_b, Wkv_b, cb);
    k_rmsnorm_x<<<8192, 256, 0, stream>>>(x, ng, xn);

    // QKV: [8192,1024] @ [5120,1024]^T -> [8192,5120]
    k_gemm8p<256, 0, 1><<<640, 512, 0, stream>>>(xn, wqkv, cb, nullptr, qkv, 8192, 5120, 1024);

    k_attn<<<2048, 256, 0, stream>>>(qkv, ob);

    k_rowss<4096><<<8192, 256, 0, stream>>>(ob, sc1);
    k_gemm8p<256, 1, 0><<<256, 512, 0, stream>>>(ob, w1, W1_b, sc1, h1, 8192, 2048, 4096);
    k_rowss<2048><<<8192, 256, 0, stream>>>(h1, sc2);
    k_gemm8p<128, 2, 0><<<256, 512, 0, stream>>>(h1, w2, W2_b, sc2, (void*)out, 8192, 1024, 2048);

    (void)in_sizes; (void)n_in; (void)out_size; (void)ws_size;
}

// Round 6
// 370.204 us; speedup vs baseline: 1.3918x; 1.0046x over previous
//
#include <hip/hip_runtime.h>
#include <cstdint>

typedef _Float16 f16;
typedef f16 f16x4 __attribute__((ext_vector_type(4)));
typedef f16 f16x8 __attribute__((ext_vector_type(8)));
typedef float f32x4 __attribute__((ext_vector_type(4)));

#define MFMA16(a, b, c) __builtin_amdgcn_mfma_f32_16x16x32_f16(a, b, c, 0, 0, 0)

static __device__ __forceinline__ void gload16(const void* g, void* l) {
    __builtin_amdgcn_global_load_lds(
        (const __attribute__((address_space(1))) uint32_t*)g,
        (__attribute__((address_space(3))) uint32_t*)l, 16, 0, 0);
}

// SGB-directed phase layout: NV VMEM (stage), then ND groups of {NM/ND MFMA, 1 DS_READ}
template <int NM, int ND, int NV>
static __device__ __forceinline__ void sgb_phase() {
    if (NV > 0) __builtin_amdgcn_sched_group_barrier(0x10, NV, 0);
    constexpr int PER = NM / ND;
#pragma unroll
    for (int i = 0; i < ND; ++i) {
        __builtin_amdgcn_sched_group_barrier(0x8, PER, 0);
        __builtin_amdgcn_sched_group_barrier(0x100, 1, 0);
    }
    if (NM - PER * ND > 0)
        __builtin_amdgcn_sched_group_barrier(0x8, NM - PER * ND, 0);
}

static __device__ __forceinline__ float blockReduceSum256(float v) {
    __shared__ float red[4];
#pragma unroll
    for (int off = 32; off > 0; off >>= 1) v += __shfl_xor(v, off);
    if ((threadIdx.x & 63) == 0) red[threadIdx.x >> 6] = v;
    __syncthreads();
    return red[0] + red[1] + red[2] + red[3];
}

// ---- rmsnorm(x f32, D=1024) -> f16 ----
__global__ __launch_bounds__(256) void k_rmsnorm_x(const float* __restrict__ x,
                                                   const float* __restrict__ gamma,
                                                   f16* __restrict__ out) {
    size_t row = blockIdx.x;
    const float4 v = reinterpret_cast<const float4*>(x + row * 1024)[threadIdx.x];
    float ss = v.x * v.x + v.y * v.y + v.z * v.z + v.w * v.w;
    ss = blockReduceSum256(ss);
    float sc = 32.0f / fmaxf(sqrtf(ss), 1e-12f);
    const float4 g = reinterpret_cast<const float4*>(gamma)[threadIdx.x];
    f16x4 o;
    o[0] = (f16)(v.x * sc * g.x); o[1] = (f16)(v.y * sc * g.y);
    o[2] = (f16)(v.z * sc * g.z); o[3] = (f16)(v.w * sc * g.w);
    *reinterpret_cast<f16x4*>(out + row * 1024 + threadIdx.x * 4) = o;
}

// ---- fused prep: weight casts (+gamma folds), bias concat, sc zeroing ----
__global__ __launch_bounds__(256) void k_prep(
    const float* __restrict__ Wq_w, const float* __restrict__ Wkv_w,
    const float* __restrict__ W1_w, const float* __restrict__ g1,
    const float* __restrict__ W2_w, const float* __restrict__ g2,
    const float* __restrict__ Wq_b, const float* __restrict__ Wkv_b,
    f16* __restrict__ wqkv, f16* __restrict__ w1, f16* __restrict__ w2,
    float* __restrict__ cb, float* __restrict__ scz) {
    int i = blockIdx.x * 256 + threadIdx.x;
    if (i < 1048576) {
        float4 v = reinterpret_cast<const float4*>(Wq_w)[i];
        f16x4 o; o[0] = (f16)v.x; o[1] = (f16)v.y; o[2] = (f16)v.z; o[3] = (f16)v.w;
        *reinterpret_cast<f16x4*>(wqkv + (size_t)i * 4) = o;
    } else if (i < 1310720) {
        int j = i - 1048576;
        float4 v = reinterpret_cast<const float4*>(Wkv_w)[j];
        f16x4 o; o[0] = (f16)v.x; o[1] = (f16)v.y; o[2] = (f16)v.z; o[3] = (f16)v.w;
        *reinterpret_cast<f16x4*>(wqkv + 4194304 + (size_t)j * 4) = o;
    } else if (i < 3407872) {
        int j = i - 1310720;
        float4 v = reinterpret_cast<const float4*>(W1_w)[j];
        int c = (j * 4) & 4095;
        f16x4 o;
        o[0] = (f16)(v.x * g1[c]);     o[1] = (f16)(v.y * g1[c + 1]);
        o[2] = (f16)(v.z * g1[c + 2]); o[3] = (f16)(v.w * g1[c + 3]);
        *reinterpret_cast<f16x4*>(w1 + (size_t)j * 4) = o;
    } else if (i < 3932160) {
        int j = i - 3407872;
        float4 v = reinterpret_cast<const float4*>(W2_w)[j];
        int c = (j * 4) & 2047;
        f16x4 o;
        o[0] = (f16)(v.x * g2[c]);     o[1] = (f16)(v.y * g2[c + 1]);
        o[2] = (f16)(v.z * g2[c + 2]); o[3] = (f16)(v.w * g2[c + 3]);
        *reinterpret_cast<f16x4*>(w2 + (size_t)j * 4) = o;
    } else if (i < 3933440) {
        int j = i - 3932160;
        int e = j * 4;
        float4 o4 = (e < 4096) ? reinterpret_cast<const float4*>(Wq_b)[j]
                               : reinterpret_cast<const float4*>(Wkv_b)[(e - 4096) >> 2];
        reinterpret_cast<float4*>(cb)[j] = o4;
    } else if (i < 3937536) {
        int j = i - 3933440;
        reinterpret_cast<float4*>(scz)[j] = make_float4(0.f, 0.f, 0.f, 0.f);
    }
}

// ==== 4-phase SGB-interleaved GEMM: C = A[M,K]@Bt[N,K]^T (+rms-scale, bias, silu) ====
// EPI 0: f16 out. EPI 1: scl(ssin)*acc+bias, silu, f16 out, accumulate ssout.
// EPI 2: scl(ssin)*acc+bias, silu, f32 out.
template <int BN, int EPI, int MODE>
__global__ __launch_bounds__(512, 2) void k_gemm8p(const f16* __restrict__ A,
                                                   const f16* __restrict__ Bt,
                                                   const float* __restrict__ bias,
                                                   const float* __restrict__ ssin,
                                                   float sqrtD,
                                                   float* __restrict__ ssout,
                                                   void* __restrict__ Cout,
                                                   int M, int N, int K) {
    constexpr int BM = 256;
    constexpr int WN = BN / 64, WM = 8 / WN, WR = BM / WM;
    constexpr int MW = WR / 16, MH = MW / 2;
    constexpr int LA = 2, LB = BN / 128;
    constexpr int VS = 2 * LA + LB;          // steady vmcnt
    constexpr int AK = BM * 32;              // elems per A K-half region
    constexpr int BKE = BN * 32;
    constexpr int SE = 2 * AK + 2 * BKE;

    __shared__ alignas(16) f16 lds[2 * SE];

    const int nb = N / BN;
    int bn, bm;
    if (MODE == 0) { bn = blockIdx.x & 7; bm = blockIdx.x >> 3; }
    else           { bn = blockIdx.x % nb; bm = blockIdx.x / nb; }

    const int tid = threadIdx.x, w = tid >> 6, l = tid & 63;
    const int wm = w / WN, wn = w % WN;
    const int lrow = l & 15, lq = l >> 4;
    const int g = (lrow >> 1) & 3;

    const f16* Ab = A + (size_t)bm * BM * K;
    const f16* Bb = Bt + (size_t)bn * BN * K;
    const int NT = K >> 6;

    int aoff[MW], boff[4];
#pragma unroll
    for (int m = 0; m < MW; ++m)
        aoff[m] = (wm * WR + m * 16 + lrow) * 32 + 8 * (lq ^ g);
#pragma unroll
    for (int n = 0; n < 4; ++n)
        boff[n] = (wn * 64 + n * 16 + lrow) * 32 + 8 * (lq ^ g);

    auto stageA = [&](int k0, f16* region) {
#pragma unroll
        for (int q = 0; q < LA; ++q) {
            int r = q * 128 + w * 16 + (l >> 2);
            int c = 8 * ((l & 3) ^ ((r >> 1) & 3));
            gload16(Ab + (size_t)r * K + k0 + c, region + q * 4096 + w * 512);
        }
    };
    auto stageB = [&](int k0, f16* region) {
#pragma unroll
        for (int q = 0; q < LB; ++q) {
            int r = q * 128 + w * 16 + (l >> 2);
            int c = 8 * ((l & 3) ^ ((r >> 1) & 3));
            gload16(Bb + (size_t)r * K + k0 + c, region + q * 4096 + w * 512);
        }
    };
    auto rdA = [&](f16x8 (&d)[MH], const f16* base, int h) {
#pragma unroll
        for (int m = 0; m < MH; ++m)
            d[m] = *reinterpret_cast<const f16x8*>(base + aoff[h * MH + m]);
    };
    auto rdB = [&](f16x8 (&d)[4], const f16* base) {
#pragma unroll
        for (int n = 0; n < 4; ++n)
            d[n] = *reinterpret_cast<const f16x8*>(base + boff[n]);
    };

    f32x4 acc[MW][4] = {};
    f16x8 afA[MH], afB[MH], bfA[4], bfB[4];

    auto mfmaLo = [&](f16x8 (&af)[MH], f16x8 (&bf)[4]) {
#pragma unroll
        for (int m = 0; m < MH; ++m)
#pragma unroll
            for (int n = 0; n < 4; ++n)
                acc[m][n] = MFMA16(af[m], bf[n], acc[m][n]);
    };
    auto mfmaHi = [&](f16x8 (&af)[MH], f16x8 (&bf)[4]) {
#pragma unroll
        for (int m = 0; m < MH; ++m)
#pragma unroll
            for (int n = 0; n < 4; ++n)
                acc[MH + m][n] = MFMA16(af[m], bf[n], acc[MH + m][n]);
    };

    // prologue: stage kk0(0), kk1(0), kk0(1); wait kk0(0); preload frags
    stageA(0, lds);             stageB(0, lds + 2 * AK);
    stageA(32, lds + AK);       stageB(32, lds + 2 * AK + BKE);
    stageA(64, lds + SE);       stageB(64, lds + SE + 2 * AK);
    asm volatile("s_waitcnt vmcnt(%0)" :: "i"(2 * (LA + LB)) : "memory");
    __builtin_amdgcn_s_barrier();
    rdA(afA, lds, 0);
    rdB(bfA, lds + 2 * AK);

    const int NTm2 = NT - 2;
    for (int t = 0; t < NTm2; ++t) {
        f16* s0 = lds + (t & 1) * SE;
        f16* s1 = lds + ((t & 1) ^ 1) * SE;
        const int kn1 = (t + 1) << 6;
        const int kn2 = (t + 2) << 6;
        // ph0: MFMA(M0,kk0) | read af1_kk0 | stage A1(t+1)
        __builtin_amdgcn_s_barrier();
        stageA(kn1 + 32, s1 + AK);
        rdA(afB, s0, 1);
        mfmaLo(afA, bfA);
        sgb_phase<MH * 4, MH, LA>();
        // ph1: MFMA(M1,kk0) | read af0_kk1 + bf_kk1 | stage B1(t+1)
        asm volatile("s_waitcnt vmcnt(%0)" :: "i"(VS) : "memory");
        __builtin_amdgcn_s_barrier();
        stageB(kn1 + 32, s1 + 2 * AK + BKE);
        rdA(afA, s0 + AK, 0);
        rdB(bfB, s0 + 2 * AK + BKE);
        mfmaHi(afB, bfA);
        sgb_phase<MH * 4, MH + 4, LB>();
        // ph2: MFMA(M0,kk1) | read af1_kk1 | stage A0(t+2)
        __builtin_amdgcn_s_barrier();
        stageA(kn2, s0);
        rdA(afB, s0 + AK, 1);
        mfmaLo(afA, bfB);
        sgb_phase<MH * 4, MH, LA>();
        // ph3: MFMA(M1,kk1) | read af0_kk0(t+1) + bf_kk0(t+1) | stage B0(t+2)
        asm volatile("s_waitcnt vmcnt(%0)" :: "i"(VS) : "memory");
        __builtin_amdgcn_s_barrier();
        stageB(kn2, s0 + 2 * AK);
        rdA(afA, s1, 0);
        rdB(bfA, s1 + 2 * AK);
        mfmaHi(afB, bfB);
        sgb_phase<MH * 4, MH + 4, LB>();
    }
    // t = NT-2 (no t+2 stages; tail waits)
    {
        const int t = NTm2;
        f16* s0 = lds + (t & 1) * SE;
        f16* s1 = lds + ((t & 1) ^ 1) * SE;
        const int kn1 = (t + 1) << 6;
        __builtin_amdgcn_s_barrier();
        stageA(kn1 + 32, s1 + AK);
        rdA(afB, s0, 1);
        mfmaLo(afA, bfA);
        sgb_phase<MH * 4, MH, LA>();
        asm volatile("s_waitcnt vmcnt(%0)" :: "i"(VS) : "memory");
        __builtin_amdgcn_s_barrier();
        stageB(kn1 + 32, s1 + 2 * AK + BKE);
        rdA(afA, s0 + AK, 0);
        rdB(bfB, s0 + 2 * AK + BKE);
        mfmaHi(afB, bfA);
        sgb_phase<MH * 4, MH + 4, LB>();
        __builtin_amdgcn_s_barrier();
        rdA(afB, s0 + AK, 1);
        mfmaLo(afA, bfB);
        sgb_phase<MH * 4, MH, 0>();
        asm volatile("s_waitcnt vmcnt(%0)" :: "i"(LA + LB) : "memory");
        __builtin_amdgcn_s_barrier();
        rdA(afA, s1, 0);
        rdB(bfA, s1 + 2 * AK);
        mfmaHi(afB, bfB);
        sgb_phase<MH * 4, MH + 4, 0>();
    }
    // t = NT-1 (no stages, final drain)
    {
        f16* s0 = lds + ((NT - 1) & 1) * SE;
        __builtin_amdgcn_s_barrier();
        rdA(afB, s0, 1);
        mfmaLo(afA, bfA);
        sgb_phase<MH * 4, MH, 0>();
        asm volatile("s_waitcnt vmcnt(0)" ::: "memory");
        __builtin_amdgcn_s_barrier();
        rdA(afA, s0 + AK, 0);
        rdB(bfB, s0 + 2 * AK + BKE);
        mfmaHi(afB, bfA);
        sgb_phase<MH * 4, MH + 4, 0>();
        __builtin_amdgcn_s_barrier();
        rdA(afB, s0 + AK, 1);
        mfmaLo(afA, bfB);
        sgb_phase<MH * 4, MH, 0>();
        mfmaHi(afB, bfB);
    }

    // epilogue
    const size_t row0 = (size_t)bm * BM + wm * WR;
    const int col0 = bn * BN + wn * 64;
    float bsv[4];
#pragma unroll
    for (int n = 0; n < 4; ++n) bsv[n] = bias[col0 + n * 16 + lrow];
#pragma unroll
    for (int m = 0; m < MW; ++m) {
#pragma unroll
        for (int r = 0; r < 4; ++r) {
            const size_t row = row0 + m * 16 + lq * 4 + r;
            float scl = 1.0f;
            if (EPI >= 1)
                scl = sqrtD / fmaxf(sqrtf(ssin[row]), 1e-12f);
            float ssp = 0.f;
#pragma unroll
            for (int n = 0; n < 4; ++n) {
                float v = acc[m][n][r];
                if (EPI >= 1) v = v * scl;
                v += bsv[n];
                if (EPI >= 1) v = v / (1.f + __expf(-v));
                if (EPI == 1) ssp += v * v;
                const size_t idx = row * N + col0 + n * 16 + lrow;
                if (EPI == 2) reinterpret_cast<float*>(Cout)[idx] = v;
                else          reinterpret_cast<f16*>(Cout)[idx] = (f16)v;
            }
            if (EPI == 1) {
                ssp += __shfl_xor(ssp, 1);
                ssp += __shfl_xor(ssp, 2);
                ssp += __shfl_xor(ssp, 4);
                ssp += __shfl_xor(ssp, 8);
                if (lrow == 0) atomicAdd(&ssout[row], ssp);
            }
        }
    }
}

// ---- windowed GQA attention from combined QKV buffer (row stride 5120) ----
// also accumulates per-row sum of squares of output into ssout (pre-zeroed)
__global__ __launch_bounds__(256) void k_attn(const f16* __restrict__ qkv,
                                              f16* __restrict__ o,
                                              float* __restrict__ ssout) {
    __shared__ alignas(16) f16 Ksm[64 * 64];
    __shared__ alignas(16) f16 Vtsm[64 * 64];
    __shared__ alignas(16) f16 Psm[4][64 * 64];
    const int idx = blockIdx.x;
    const int s = idx & 127;
    const int g = (idx >> 7) & 7;
    const int b = idx >> 10;
    const int tid = threadIdx.x;
    const int w = tid >> 6, l = tid & 63;

    const int baseR = s * 32 - 16;
#pragma unroll
    for (int i = 0; i < 2; ++i) {
        const int j = i * 32 + (tid >> 3);
        const int d0 = (tid & 7) * 8;
        const int R = baseR + j;
        f16x8 kvv = {}, vvv = {};
        if (R >= 0 && R < 4096) {
            const f16* rp = qkv + ((size_t)(b * 4096 + R)) * 5120 + 4096 + g * 64 + d0;
            kvv = *reinterpret_cast<const f16x8*>(rp);
            vvv = *reinterpret_cast<const f16x8*>(rp + 512);
        }
        *reinterpret_cast<f16x8*>(&Ksm[j * 64 + d0]) = kvv;
#pragma unroll
        for (int e = 0; e < 8; ++e) Vtsm[(d0 + e) * 64 + j] = vvv[e];
    }

    const int lrow = l & 15, lk = (l >> 4) * 8;
    f16x8 aq[4][2];
#pragma unroll
    for (int m = 0; m < 4; ++m) {
        const int qr = w * 64 + m * 16 + lrow;
        const int h = qr >> 5, qi = qr & 31;
        const f16* qp = qkv + ((size_t)(b * 4096 + s * 32 + qi)) * 5120 + (g * 8 + h) * 64 + lk;
        aq[m][0] = *reinterpret_cast<const f16x8*>(qp);
        aq[m][1] = *reinterpret_cast<const f16x8*>(qp + 32);
    }
    __syncthreads();

    f32x4 acc[4][4] = {};
#pragma unroll
    for (int kk = 0; kk < 2; ++kk) {
        f16x8 bk[4];
#pragma unroll
        for (int n = 0; n < 4; ++n)
            bk[n] = *reinterpret_cast<const f16x8*>(&Ksm[(n * 16 + lrow) * 64 + kk * 32 + lk]);
#pragma unroll
        for (int m = 0; m < 4; ++m)
#pragma unroll
            for (int n = 0; n < 4; ++n)
                acc[m][n] = MFMA16(aq[m][kk], bk[n], acc[m][n]);
    }

    const int nlo = (s == 0) ? 1 : 0;
    const int nhi = (s == 127) ? 3 : 4;
#pragma unroll
    for (int m = 0; m < 4; ++m) {
#pragma unroll
        for (int r = 0; r < 4; ++r) {
            float xv[4];
#pragma unroll
            for (int n = 0; n < 4; ++n) xv[n] = acc[m][n][r] * 0.125f;
            float mx = -1e30f;
            for (int n = nlo; n < nhi; ++n) mx = fmaxf(mx, xv[n]);
#pragma unroll
            for (int off = 8; off > 0; off >>= 1) mx = fmaxf(mx, __shfl_xor(mx, off));
            float pv[4]; float sum = 0.f;
#pragma unroll
            for (int n = 0; n < 4; ++n) {
                float e = (n >= nlo && n < nhi) ? __expf(xv[n] - mx) : 0.f;
                pv[n] = e; sum += e;
            }
#pragma unroll
            for (int off = 8; off > 0; off >>= 1) sum += __shfl_xor(sum, off);
            const float inv = 1.f / sum;
            const int prow = m * 16 + (l >> 4) * 4 + r;
#pragma unroll
            for (int n = 0; n < 4; ++n)
                Psm[w][prow * 64 + n * 16 + lrow] = (f16)(pv[n] * inv);
        }
    }
    __syncthreads();

    f32x4 oacc[4][4] = {};
#pragma unroll
    for (int kk = 0; kk < 2; ++kk) {
        f16x8 ap[4], bv[4];
#pragma unroll
        for (int m = 0; m < 4; ++m)
            ap[m] = *reinterpret_cast<const f16x8*>(&Psm[w][(m * 16 + lrow) * 64 + kk * 32 + lk]);
#pragma unroll
        for (int n = 0; n < 4; ++n)
            bv[n] = *reinterpret_cast<const f16x8*>(&Vtsm[(n * 16 + lrow) * 64 + kk * 32 + lk]);
#pragma unroll
        for (int m = 0; m < 4; ++m)
#pragma unroll
            for (int n = 0; n < 4; ++n)
                oacc[m][n] = MFMA16(ap[m], bv[n], oacc[m][n]);
    }
    const int lr4 = (l >> 4) * 4;
#pragma unroll
    for (int m = 0; m < 4; ++m) {
#pragma unroll
        for (int r = 0; r < 4; ++r) {
            const int qr = w * 64 + m * 16 + lr4 + r;
            const int h = qr >> 5, qi = qr & 31;
            f16* op = o + ((size_t)(b * 4096 + s * 32 + qi)) * 4096 + (g * 8 + h) * 64;
            float ssp = 0.f;
#pragma unroll
            for (int n = 0; n < 4; ++n) {
                float v = oacc[m][n][r];
                op[n * 16 + lrow] = (f16)v;
                ssp += v * v;
            }
            ssp += __shfl_xor(ssp, 1);
            ssp += __shfl_xor(ssp, 2);
            ssp += __shfl_xor(ssp, 4);
            ssp += __shfl_xor(ssp, 8);
            if (lrow == 0)
                atomicAdd(&ssout[(size_t)(b * 4096 + s * 32 + qi)], ssp);
        }
    }
}

extern "C" void kernel_launch(void* const* d_in, const int* in_sizes, int n_in,
                              void* d_out, int out_size, void* d_ws, size_t ws_size,
                              hipStream_t stream) {
    const float* x     = (const float*)d_in[0];
    const float* ng    = (const float*)d_in[1];
    const float* Wq_w  = (const float*)d_in[2];
    const float* Wq_b  = (const float*)d_in[3];
    const float* Wkv_w = (const float*)d_in[4];
    const float* Wkv_b = (const float*)d_in[5];
    const float* g1    = (const float*)d_in[6];
    const float* W1_w  = (const float*)d_in[7];
    const float* W1_b  = (const float*)d_in[8];
    const float* g2    = (const float*)d_in[9];
    const float* W2_w  = (const float*)d_in[10];
    const float* W2_b  = (const float*)d_in[11];
    float* out = (float*)d_out;

    char* p = (char*)d_ws;
    f16* qkv  = (f16*)(p);                 // [8192][5120] 80 MB
    f16* h1   = (f16*)(p);                 // [8192][2048] (over qkv, after attn)
    f16* xn   = (f16*)(p + 83886080);      // [8192][1024]
    f16* ob   = (f16*)(p + 83886080);      // [8192][4096] (over xn, written by attn)
    f16* w1   = (f16*)(p + 150994944);     // 16 MB
    f16* w2   = (f16*)(p + 167772160);     // 4 MB
    f16* wqkv = (f16*)(p + 171966464);     // [5120][1024] 10 MB
    float* cb  = (float*)(p + 182452224);  // [5120]
    float* sc1 = (float*)(p + 182472704);  // [8192]  (sc1+sc2 contiguous for zeroing)
    float* sc2 = (float*)(p + 182505472);  // [8192]

    // one fused prep kernel: all weight casts (+gamma folds), bias concat, sc zeroing
    k_prep<<<15381, 256, 0, stream>>>(Wq_w, Wkv_w, W1_w, g1, W2_w, g2, Wq_b, Wkv_b,
                                      wqkv, w1, w2, cb, sc1);
    k_rmsnorm_x<<<8192, 256, 0, stream>>>(x, ng, xn);

    // QKV: [8192,1024] @ [5120,1024]^T -> [8192,5120]
    k_gemm8p<256, 0, 1><<<640, 512, 0, stream>>>(xn, wqkv, cb, nullptr, 0.f, nullptr,
                                                 qkv, 8192, 5120, 1024);

    // attention (writes ob, accumulates sc1 = per-row ss of ob)
    k_attn<<<2048, 256, 0, stream>>>(qkv, ob, sc1);

    // FF1: silu(scl(sc1)*(ob @ (g1.W1)^T) + b1) -> h1 ; accumulates sc2
    k_gemm8p<256, 1, 0><<<256, 512, 0, stream>>>(ob, w1, W1_b, sc1, 64.0f, sc2,
                                                 h1, 8192, 2048, 4096);
    // FF2: silu(scl(sc2)*(h1 @ (g2.W2)^T) + b2) -> out f32
    k_gemm8p<128, 2, 0><<<256, 512, 0, stream>>>(h1, w2, W2_b, sc2, 45.254834f, nullptr,
                                                 (void*)out, 8192, 1024, 2048);

    (void)in_sizes; (void)n_in; (void)out_size; (void)ws_size;
}

// Round 7
// 366.687 us; speedup vs baseline: 1.4052x; 1.0096x over previous
//
#include <hip/hip_runtime.h>
#include <cstdint>

typedef _Float16 f16;
typedef f16 f16x4 __attribute__((ext_vector_type(4)));
typedef f16 f16x8 __attribute__((ext_vector_type(8)));
typedef float f32x4 __attribute__((ext_vector_type(4)));
typedef float f32x16 __attribute__((ext_vector_type(16)));

#define MFMA16(a, b, c) __builtin_amdgcn_mfma_f32_16x16x32_f16(a, b, c, 0, 0, 0)
#define MFMA32(a, b, c) __builtin_amdgcn_mfma_f32_32x32x16_f16(a, b, c, 0, 0, 0)

static __device__ __forceinline__ void gload16(const void* g, void* l) {
    __builtin_amdgcn_global_load_lds(
        (const __attribute__((address_space(1))) uint32_t*)g,
        (__attribute__((address_space(3))) uint32_t*)l, 16, 0, 0);
}

// SGB-directed phase layout: NV VMEM (stage), then ND groups of {NM/ND MFMA, 1 DS_READ}
template <int NM, int ND, int NV>
static __device__ __forceinline__ void sgb_phase() {
    if (NV > 0) __builtin_amdgcn_sched_group_barrier(0x10, NV, 0);
    constexpr int PER = NM / ND;
#pragma unroll
    for (int i = 0; i < ND; ++i) {
        __builtin_amdgcn_sched_group_barrier(0x8, PER, 0);
        __builtin_amdgcn_sched_group_barrier(0x100, 1, 0);
    }
    if (NM - PER * ND > 0)
        __builtin_amdgcn_sched_group_barrier(0x8, NM - PER * ND, 0);
}

static __device__ __forceinline__ float blockReduceSum256(float v) {
    __shared__ float red[4];
#pragma unroll
    for (int off = 32; off > 0; off >>= 1) v += __shfl_xor(v, off);
    if ((threadIdx.x & 63) == 0) red[threadIdx.x >> 6] = v;
    __syncthreads();
    return red[0] + red[1] + red[2] + red[3];
}

// ---- rmsnorm(x f32, D=1024) -> f16 ----
__global__ __launch_bounds__(256) void k_rmsnorm_x(const float* __restrict__ x,
                                                   const float* __restrict__ gamma,
                                                   f16* __restrict__ out) {
    size_t row = blockIdx.x;
    const float4 v = reinterpret_cast<const float4*>(x + row * 1024)[threadIdx.x];
    float ss = v.x * v.x + v.y * v.y + v.z * v.z + v.w * v.w;
    ss = blockReduceSum256(ss);
    float sc = 32.0f / fmaxf(sqrtf(ss), 1e-12f);
    const float4 g = reinterpret_cast<const float4*>(gamma)[threadIdx.x];
    f16x4 o;
    o[0] = (f16)(v.x * sc * g.x); o[1] = (f16)(v.y * sc * g.y);
    o[2] = (f16)(v.z * sc * g.z); o[3] = (f16)(v.w * sc * g.w);
    *reinterpret_cast<f16x4*>(out + row * 1024 + threadIdx.x * 4) = o;
}

// ---- per-row scale input: ss[row] = sum of squares ----
template <int D>
__global__ __launch_bounds__(256) void k_rowss(const f16* __restrict__ in,
                                               float* __restrict__ sc) {
    constexpr int PER = D / 256;
    size_t row = blockIdx.x;
    const f16* ir = in + row * D;
    int c0 = threadIdx.x * PER;
    float ss = 0.f;
#pragma unroll
    for (int i = 0; i < PER; i += 8) {
        f16x8 h = *reinterpret_cast<const f16x8*>(ir + c0 + i);
#pragma unroll
        for (int e = 0; e < 8; ++e) { float f = (float)h[e]; ss += f * f; }
    }
    ss = blockReduceSum256(ss);
    if (threadIdx.x == 0) sc[row] = ss;
}

// ---- fused prep: weight casts (+gamma folds), bias concat, sc zeroing ----
__global__ __launch_bounds__(256) void k_prep(
    const float* __restrict__ Wq_w, const float* __restrict__ Wkv_w,
    const float* __restrict__ W1_w, const float* __restrict__ g1,
    const float* __restrict__ W2_w, const float* __restrict__ g2,
    const float* __restrict__ Wq_b, const float* __restrict__ Wkv_b,
    f16* __restrict__ wqkv, f16* __restrict__ w1, f16* __restrict__ w2,
    float* __restrict__ cb, float* __restrict__ scz) {
    int i = blockIdx.x * 256 + threadIdx.x;
    if (i < 1048576) {
        float4 v = reinterpret_cast<const float4*>(Wq_w)[i];
        f16x4 o; o[0] = (f16)v.x; o[1] = (f16)v.y; o[2] = (f16)v.z; o[3] = (f16)v.w;
        *reinterpret_cast<f16x4*>(wqkv + (size_t)i * 4) = o;
    } else if (i < 1310720) {
        int j = i - 1048576;
        float4 v = reinterpret_cast<const float4*>(Wkv_w)[j];
        f16x4 o; o[0] = (f16)v.x; o[1] = (f16)v.y; o[2] = (f16)v.z; o[3] = (f16)v.w;
        *reinterpret_cast<f16x4*>(wqkv + 4194304 + (size_t)j * 4) = o;
    } else if (i < 3407872) {
        int j = i - 1310720;
        float4 v = reinterpret_cast<const float4*>(W1_w)[j];
        int c = (j * 4) & 4095;
        f16x4 o;
        o[0] = (f16)(v.x * g1[c]);     o[1] = (f16)(v.y * g1[c + 1]);
        o[2] = (f16)(v.z * g1[c + 2]); o[3] = (f16)(v.w * g1[c + 3]);
        *reinterpret_cast<f16x4*>(w1 + (size_t)j * 4) = o;
    } else if (i < 3932160) {
        int j = i - 3407872;
        float4 v = reinterpret_cast<const float4*>(W2_w)[j];
        int c = (j * 4) & 2047;
        f16x4 o;
        o[0] = (f16)(v.x * g2[c]);     o[1] = (f16)(v.y * g2[c + 1]);
        o[2] = (f16)(v.z * g2[c + 2]); o[3] = (f16)(v.w * g2[c + 3]);
        *reinterpret_cast<f16x4*>(w2 + (size_t)j * 4) = o;
    } else if (i < 3933440) {
        int j = i - 3932160;
        int e = j * 4;
        float4 o4 = (e < 4096) ? reinterpret_cast<const float4*>(Wq_b)[j]
                               : reinterpret_cast<const float4*>(Wkv_b)[(e - 4096) >> 2];
        reinterpret_cast<float4*>(cb)[j] = o4;
    } else if (i < 3937536) {
        int j = i - 3933440;
        reinterpret_cast<float4*>(scz)[j] = make_float4(0.f, 0.f, 0.f, 0.f);
    }
}

// ==== 4-phase SGB-interleaved GEMM, 32x32x16 MFMA, XCD-chunked mapping ====
// C[M,N] = (EPI>=1: rms(ssin)-scale) A[M,K]@Bt[N,K]^T + bias (+silu)
// EPI 0: f16 out. EPI 1: f16 out + scale/silu. EPI 2: f32 out + scale/silu.
template <int BN, int EPI>
__global__ __launch_bounds__(512, 2) void k_gemm32(const f16* __restrict__ A,
                                                   const f16* __restrict__ Bt,
                                                   const float* __restrict__ bias,
                                                   const float* __restrict__ ssin,
                                                   float sqrtD,
                                                   void* __restrict__ Cout,
                                                   int M, int N, int K) {
    constexpr int BM = 256;
    constexpr int WN = BN / 64, WM = 8 / WN;
    constexpr int WR = BM / WM, WC = BN / WN;      // wave tile
    constexpr int MA = WR / 32, NB = WC / 32;      // 32x32 frags per wave
    constexpr int LA = 2, LB = BN / 128;
    constexpr int VS = 2 * LA + LB;
    constexpr int AK = BM * 32, BKE = BN * 32;
    constexpr int SE = 2 * AK + 2 * BKE;

    __shared__ alignas(16) f16 lds[2 * SE];

    // XCD-chunked mapping: all bn-blocks of one bm-stripe live in one XCD
    const int mb = M / BM;
    const int cpx = mb >> 3;                       // bm per XCD
    const int xcd = blockIdx.x & 7;
    const int j = blockIdx.x >> 3;
    const int bm = xcd * cpx + (j % cpx);
    const int bn = j / cpx;

    const int tid = threadIdx.x, w = tid >> 6, l = tid & 63;
    const int wm = w / WN, wn = w % WN;
    const int cl = l & 31, h = l >> 5;

    const f16* Ab = A + (size_t)bm * BM * K;
    const f16* Bb = Bt + (size_t)bn * BN * K;
    const int NT = K >> 6;

    int aoff[MA][2], boff[NB][2];
#pragma unroll
    for (int m = 0; m < MA; ++m) {
        int r = wm * WR + m * 32 + cl;
        int gg = (r >> 1) & 3;
        aoff[m][0] = r * 32 + 8 * (h ^ gg);
        aoff[m][1] = r * 32 + 8 * ((2 | h) ^ gg);
    }
#pragma unroll
    for (int n = 0; n < NB; ++n) {
        int r = wn * WC + n * 32 + cl;
        int gg = (r >> 1) & 3;
        boff[n][0] = r * 32 + 8 * (h ^ gg);
        boff[n][1] = r * 32 + 8 * ((2 | h) ^ gg);
    }

    auto stageA = [&](int k0, f16* region) {
#pragma unroll
        for (int q = 0; q < LA; ++q) {
            int r = q * 128 + w * 16 + (l >> 2);
            int c = 8 * ((l & 3) ^ ((r >> 1) & 3));
            gload16(Ab + (size_t)r * K + k0 + c, region + q * 4096 + w * 512);
        }
    };
    auto stageB = [&](int k0, f16* region) {
#pragma unroll
        for (int q = 0; q < LB; ++q) {
            int r = q * 128 + w * 16 + (l >> 2);
            int c = 8 * ((l & 3) ^ ((r >> 1) & 3));
            gload16(Bb + (size_t)r * K + k0 + c, region + q * 4096 + w * 512);
        }
    };

    f32x16 acc[MA][NB] = {};
    f16x8 afA[MA], afB[MA], bfA[NB], bfB[NB];

    auto rdA = [&](f16x8 (&d)[MA], const f16* base, int p) {
#pragma unroll
        for (int m = 0; m < MA; ++m)
            d[m] = *reinterpret_cast<const f16x8*>(base + aoff[m][p]);
    };
    auto rdB = [&](f16x8 (&d)[NB], const f16* base, int p) {
#pragma unroll
        for (int n = 0; n < NB; ++n)
            d[n] = *reinterpret_cast<const f16x8*>(base + boff[n][p]);
    };
    auto domfma = [&](f16x8 (&af)[MA], f16x8 (&bf)[NB]) {
#pragma unroll
        for (int m = 0; m < MA; ++m)
#pragma unroll
            for (int n = 0; n < NB; ++n)
                acc[m][n] = MFMA32(af[m], bf[n], acc[m][n]);
    };

    // prologue: stage kk0(0), kk1(0), kk0(1); wait kk0(0); preload ks0 frags
    stageA(0, lds);             stageB(0, lds + 2 * AK);
    stageA(32, lds + AK);       stageB(32, lds + 2 * AK + BKE);
    stageA(64, lds + SE);       stageB(64, lds + SE + 2 * AK);
    asm volatile("s_waitcnt vmcnt(%0)" :: "i"(2 * (LA + LB)) : "memory");
    __builtin_amdgcn_s_barrier();
    rdA(afA, lds, 0);
    rdB(bfA, lds + 2 * AK, 0);

    for (int t = 0; t < NT - 2; ++t) {
        f16* s0 = lds + (t & 1) * SE;
        f16* s1 = lds + ((t & 1) ^ 1) * SE;
        const int kn1 = (t + 1) << 6;
        const int kn2 = (t + 2) << 6;
        // ph0: MFMA ks0 | read ks1 | stage A1(t+1)
        __builtin_amdgcn_s_barrier();
        stageA(kn1 + 32, s1 + AK);
        rdA(afB, s0, 1); rdB(bfB, s0 + 2 * AK, 1);
        domfma(afA, bfA);
        sgb_phase<MA * NB, MA + NB, LA>();
        // ph1: MFMA ks1 | read ks2 (kk1 t) | stage B1(t+1)
        asm volatile("s_waitcnt vmcnt(%0)" :: "i"(VS) : "memory");
        __builtin_amdgcn_s_barrier();
        stageB(kn1 + 32, s1 + 2 * AK + BKE);
        rdA(afA, s0 + AK, 0); rdB(bfA, s0 + 2 * AK + BKE, 0);
        domfma(afB, bfB);
        sgb_phase<MA * NB, MA + NB, LB>();
        // ph2: MFMA ks2 | read ks3 | stage A0(t+2)
        __builtin_amdgcn_s_barrier();
        stageA(kn2, s0);
        rdA(afB, s0 + AK, 1); rdB(bfB, s0 + 2 * AK + BKE, 1);
        domfma(afA, bfA);
        sgb_phase<MA * NB, MA + NB, LA>();
        // ph3: MFMA ks3 | read ks0(t+1) | stage B0(t+2)
        asm volatile("s_waitcnt vmcnt(%0)" :: "i"(VS) : "memory");
        __builtin_amdgcn_s_barrier();
        stageB(kn2, s0 + 2 * AK);
        rdA(afA, s1, 0); rdB(bfA, s1 + 2 * AK, 0);
        domfma(afB, bfB);
        sgb_phase<MA * NB, MA + NB, LB>();
    }
    // t = NT-2: no t+2 stages; tail waits
    {
        const int t = NT - 2;
        f16* s0 = lds + (t & 1) * SE;
        f16* s1 = lds + ((t & 1) ^ 1) * SE;
        const int kn1 = (t + 1) << 6;
        __builtin_amdgcn_s_barrier();
        stageA(kn1 + 32, s1 + AK);
        rdA(afB, s0, 1); rdB(bfB, s0 + 2 * AK, 1);
        domfma(afA, bfA);
        sgb_phase<MA * NB, MA + NB, LA>();
        asm volatile("s_waitcnt vmcnt(%0)" :: "i"(VS) : "memory");
        __builtin_amdgcn_s_barrier();
        stageB(kn1 + 32, s1 + 2 * AK + BKE);
        rdA(afA, s0 + AK, 0); rdB(bfA, s0 + 2 * AK + BKE, 0);
        domfma(afB, bfB);
        sgb_phase<MA * NB, MA + NB, LB>();
        __builtin_amdgcn_s_barrier();
        rdA(afB, s0 + AK, 1); rdB(bfB, s0 + 2 * AK + BKE, 1);
        domfma(afA, bfA);
        sgb_phase<MA * NB, MA + NB, 0>();
        asm volatile("s_waitcnt vmcnt(%0)" :: "i"(LA + LB) : "memory");
        __builtin_amdgcn_s_barrier();
        rdA(afA, s1, 0); rdB(bfA, s1 + 2 * AK, 0);
        domfma(afB, bfB);
        sgb_phase<MA * NB, MA + NB, 0>();
    }
    // t = NT-1: final drain
    {
        f16* s0 = lds + ((NT - 1) & 1) * SE;
        __builtin_amdgcn_s_barrier();
        rdA(afB, s0, 1); rdB(bfB, s0 + 2 * AK, 1);
        domfma(afA, bfA);
        sgb_phase<MA * NB, MA + NB, 0>();
        asm volatile("s_waitcnt vmcnt(0)" ::: "memory");
        __builtin_amdgcn_s_barrier();
        rdA(afA, s0 + AK, 0); rdB(bfA, s0 + 2 * AK + BKE, 0);
        domfma(afB, bfB);
        sgb_phase<MA * NB, MA + NB, 0>();
        rdA(afB, s0 + AK, 1); rdB(bfB, s0 + 2 * AK + BKE, 1);
        domfma(afA, bfA);
        sgb_phase<MA * NB, MA + NB, 0>();
        domfma(afB, bfB);
    }

    // epilogue (32x32 C layout: col = cl, row = (reg&3) + 8*(reg>>2) + 4*h)
    const size_t row0 = (size_t)bm * BM + wm * WR;
    const int col0 = bn * BN + wn * WC;
    float bsv[NB];
#pragma unroll
    for (int n = 0; n < NB; ++n) bsv[n] = bias[col0 + n * 32 + cl];
#pragma unroll
    for (int m = 0; m < MA; ++m) {
#pragma unroll
        for (int jr = 0; jr < 16; ++jr) {
            const size_t row = row0 + m * 32 + h * 4 + (jr & 3) + 8 * (jr >> 2);
            float scl = 1.0f;
            if (EPI >= 1) scl = sqrtD * rsqrtf(fmaxf(ssin[row], 1e-24f));
#pragma unroll
            for (int n = 0; n < NB; ++n) {
                float v = acc[m][n][jr];
                if (EPI >= 1) v = v * scl;
                v += bsv[n];
                if (EPI >= 1) v = v / (1.f + __expf(-v));
                const size_t idx = row * (size_t)N + col0 + n * 32 + cl;
                if (EPI == 2) reinterpret_cast<float*>(Cout)[idx] = v;
                else          reinterpret_cast<f16*>(Cout)[idx] = (f16)v;
            }
        }
    }
}

// ---- windowed GQA attention from combined QKV buffer (row stride 5120) ----
// also accumulates per-row sum of squares of output into ssout (pre-zeroed)
__global__ __launch_bounds__(256) void k_attn(const f16* __restrict__ qkv,
                                              f16* __restrict__ o,
                                              float* __restrict__ ssout) {
    __shared__ alignas(16) f16 Ksm[64 * 64];
    __shared__ alignas(16) f16 Vtsm[64 * 64];
    __shared__ alignas(16) f16 Psm[4][64 * 64];
    const int idx = blockIdx.x;
    const int s = idx & 127;
    const int g = (idx >> 7) & 7;
    const int b = idx >> 10;
    const int tid = threadIdx.x;
    const int w = tid >> 6, l = tid & 63;

    const int baseR = s * 32 - 16;
#pragma unroll
    for (int i = 0; i < 2; ++i) {
        const int j = i * 32 + (tid >> 3);
        const int d0 = (tid & 7) * 8;
        const int R = baseR + j;
        f16x8 kvv = {}, vvv = {};
        if (R >= 0 && R < 4096) {
            const f16* rp = qkv + ((size_t)(b * 4096 + R)) * 5120 + 4096 + g * 64 + d0;
            kvv = *reinterpret_cast<const f16x8*>(rp);
            vvv = *reinterpret_cast<const f16x8*>(rp + 512);
        }
        *reinterpret_cast<f16x8*>(&Ksm[j * 64 + d0]) = kvv;
#pragma unroll
        for (int e = 0; e < 8; ++e) Vtsm[(d0 + e) * 64 + j] = vvv[e];
    }

    const int lrow = l & 15, lk = (l >> 4) * 8;
    f16x8 aq[4][2];
#pragma unroll
    for (int m = 0; m < 4; ++m) {
        const int qr = w * 64 + m * 16 + lrow;
        const int h = qr >> 5, qi = qr & 31;
        const f16* qp = qkv + ((size_t)(b * 4096 + s * 32 + qi)) * 5120 + (g * 8 + h) * 64 + lk;
        aq[m][0] = *reinterpret_cast<const f16x8*>(qp);
        aq[m][1] = *reinterpret_cast<const f16x8*>(qp + 32);
    }
    __syncthreads();

    f32x4 acc[4][4] = {};
#pragma unroll
    for (int kk = 0; kk < 2; ++kk) {
        f16x8 bk[4];
#pragma unroll
        for (int n = 0; n < 4; ++n)
            bk[n] = *reinterpret_cast<const f16x8*>(&Ksm[(n * 16 + lrow) * 64 + kk * 32 + lk]);
#pragma unroll
        for (int m = 0; m < 4; ++m)
#pragma unroll
            for (int n = 0; n < 4; ++n)
                acc[m][n] = MFMA16(aq[m][kk], bk[n], acc[m][n]);
    }

    const int nlo = (s == 0) ? 1 : 0;
    const int nhi = (s == 127) ? 3 : 4;
#pragma unroll
    for (int m = 0; m < 4; ++m) {
#pragma unroll
        for (int r = 0; r < 4; ++r) {
            float xv[4];
#pragma unroll
            for (int n = 0; n < 4; ++n) xv[n] = acc[m][n][r] * 0.125f;
            float mx = -1e30f;
            for (int n = nlo; n < nhi; ++n) mx = fmaxf(mx, xv[n]);
#pragma unroll
            for (int off = 8; off > 0; off >>= 1) mx = fmaxf(mx, __shfl_xor(mx, off));
            float pv[4]; float sum = 0.f;
#pragma unroll
            for (int n = 0; n < 4; ++n) {
                float e = (n >= nlo && n < nhi) ? __expf(xv[n] - mx) : 0.f;
                pv[n] = e; sum += e;
            }
#pragma unroll
            for (int off = 8; off > 0; off >>= 1) sum += __shfl_xor(sum, off);
            const float inv = 1.f / sum;
            const int prow = m * 16 + (l >> 4) * 4 + r;
#pragma unroll
            for (int n = 0; n < 4; ++n)
                Psm[w][prow * 64 + n * 16 + lrow] = (f16)(pv[n] * inv);
        }
    }
    __syncthreads();

    f32x4 oacc[4][4] = {};
#pragma unroll
    for (int kk = 0; kk < 2; ++kk) {
        f16x8 ap[4], bv[4];
#pragma unroll
        for (int m = 0; m < 4; ++m)
            ap[m] = *reinterpret_cast<const f16x8*>(&Psm[w][(m * 16 + lrow) * 64 + kk * 32 + lk]);
#pragma unroll
        for (int n = 0; n < 4; ++n)
            bv[n] = *reinterpret_cast<const f16x8*>(&Vtsm[(n * 16 + lrow) * 64 + kk * 32 + lk]);
#pragma unroll
        for (int m = 0; m < 4; ++m)
#pragma unroll
            for (int n = 0; n < 4; ++n)
                oacc[m][n] = MFMA16(ap[m], bv[n], oacc[m][n]);
    }
    const int lr4 = (l >> 4) * 4;
#pragma unroll
    for (int m = 0; m < 4; ++m) {
#pragma unroll
        for (int r = 0; r < 4; ++r) {
            const int qr = w * 64 + m * 16 + lr4 + r;
            const int h = qr >> 5, qi = qr & 31;
            f16* op = o + ((size_t)(b * 4096 + s * 32 + qi)) * 4096 + (g * 8 + h) * 64;
            float ssp = 0.f;
#pragma unroll
            for (int n = 0; n < 4; ++n) {
                float v = oacc[m][n][r];
                op[n * 16 + lrow] = (f16)v;
                ssp += v * v;
            }
            ssp += __shfl_xor(ssp, 1);
            ssp += __shfl_xor(ssp, 2);
            ssp += __shfl_xor(ssp, 4);
            ssp += __shfl_xor(ssp, 8);
            if (lrow == 0)
                atomicAdd(&ssout[(size_t)(b * 4096 + s * 32 + qi)], ssp);
        }
    }
}

extern "C" void kernel_launch(void* const* d_in, const int* in_sizes, int n_in,
                              void* d_out, int out_size, void* d_ws, size_t ws_size,
                              hipStream_t stream) {
    const float* x     = (const float*)d_in[0];
    const float* ng    = (const float*)d_in[1];
    const float* Wq_w  = (const float*)d_in[2];
    const float* Wq_b  = (const float*)d_in[3];
    const float* Wkv_w = (const float*)d_in[4];
    const float* Wkv_b = (const float*)d_in[5];
    const float* g1    = (const float*)d_in[6];
    const float* W1_w  = (const float*)d_in[7];
    const float* W1_b  = (const float*)d_in[8];
    const float* g2    = (const float*)d_in[9];
    const float* W2_w  = (const float*)d_in[10];
    const float* W2_b  = (const float*)d_in[11];
    float* out = (float*)d_out;

    char* p = (char*)d_ws;
    f16* qkv  = (f16*)(p);                 // [8192][5120] 80 MB
    f16* h1   = (f16*)(p);                 // [8192][2048] (over qkv, after attn)
    f16* xn   = (f16*)(p + 83886080);      // [8192][1024]
    f16* ob   = (f16*)(p + 83886080);      // [8192][4096] (over xn, written by attn)
    f16* w1   = (f16*)(p + 150994944);     // 16 MB
    f16* w2   = (f16*)(p + 167772160);     // 4 MB
    f16* wqkv = (f16*)(p + 171966464);     // [5120][1024] 10 MB
    float* cb  = (float*)(p + 182452224);  // [5120]
    float* sc1 = (float*)(p + 182472704);  // [8192]
    float* sc2 = (float*)(p + 182505472);  // [8192]

    k_prep<<<15381, 256, 0, stream>>>(Wq_w, Wkv_w, W1_w, g1, W2_w, g2, Wq_b, Wkv_b,
                                      wqkv, w1, w2, cb, sc1);
    k_rmsnorm_x<<<8192, 256, 0, stream>>>(x, ng, xn);

    // QKV: [8192,1024] @ [5120,1024]^T -> [8192,5120]
    k_gemm32<256, 0><<<640, 512, 0, stream>>>(xn, wqkv, cb, nullptr, 0.f,
                                              qkv, 8192, 5120, 1024);

    // attention (writes ob, accumulates sc1 = per-row ss of ob)
    k_attn<<<2048, 256, 0, stream>>>(qkv, ob, sc1);

    // FF1: silu(scl(sc1)*(ob @ (g1.W1)^T) + b1) -> h1
    k_gemm32<256, 1><<<256, 512, 0, stream>>>(ob, w1, W1_b, sc1, 64.0f,
                                              h1, 8192, 2048, 4096);
    k_rowss<2048><<<8192, 256, 0, stream>>>(h1, sc2);
    // FF2: silu(scl(sc2)*(h1 @ (g2.W2)^T) + b2) -> out f32
    k_gemm32<128, 2><<<256, 512, 0, stream>>>(h1, w2, W2_b, sc2, 45.254834f,
                                              (void*)out, 8192, 1024, 2048);

    (void)in_sizes; (void)n_in; (void)out_size; (void)ws_size;
}

// Round 8
// 345.787 us; speedup vs baseline: 1.4901x; 1.0604x over previous
//
#include <hip/hip_runtime.h>
#include <cstdint>

typedef _Float16 f16;
typedef f16 f16x4 __attribute__((ext_vector_type(4)));
typedef f16 f16x8 __attribute__((ext_vector_type(8)));
typedef float f32x4 __attribute__((ext_vector_type(4)));

#define MFMA16(a, b, c) __builtin_amdgcn_mfma_f32_16x16x32_f16(a, b, c, 0, 0, 0)

static __device__ __forceinline__ void gload16(const void* g, void* l) {
    __builtin_amdgcn_global_load_lds(
        (const __attribute__((address_space(1))) uint32_t*)g,
        (__attribute__((address_space(3))) uint32_t*)l, 16, 0, 0);
}

// SGB-directed phase layout: NV VMEM (stage), then ND groups of {NM/ND MFMA, 1 DS_READ}
template <int NM, int ND, int NV>
static __device__ __forceinline__ void sgb_phase() {
    if (NV > 0) __builtin_amdgcn_sched_group_barrier(0x10, NV, 0);
    constexpr int PER = NM / ND;
#pragma unroll
    for (int i = 0; i < ND; ++i) {
        __builtin_amdgcn_sched_group_barrier(0x8, PER, 0);
        __builtin_amdgcn_sched_group_barrier(0x100, 1, 0);
    }
    if (NM - PER * ND > 0)
        __builtin_amdgcn_sched_group_barrier(0x8, NM - PER * ND, 0);
}

static __device__ __forceinline__ float blockReduceSum256(float v) {
    __shared__ float red[4];
#pragma unroll
    for (int off = 32; off > 0; off >>= 1) v += __shfl_xor(v, off);
    if ((threadIdx.x & 63) == 0) red[threadIdx.x >> 6] = v;
    __syncthreads();
    return red[0] + red[1] + red[2] + red[3];
}

// ---- per-row ss: sc[row] = sum of squares ----
template <int D>
__global__ __launch_bounds__(256) void k_rowss(const f16* __restrict__ in,
                                               float* __restrict__ sc) {
    constexpr int PER = D / 256;
    size_t row = blockIdx.x;
    const f16* ir = in + row * D;
    int c0 = threadIdx.x * PER;
    float ss = 0.f;
#pragma unroll
    for (int i = 0; i < PER; i += 8) {
        f16x8 h = *reinterpret_cast<const f16x8*>(ir + c0 + i);
#pragma unroll
        for (int e = 0; e < 8; ++e) { float f = (float)h[e]; ss += f * f; }
    }
    ss = blockReduceSum256(ss);
    if (threadIdx.x == 0) sc[row] = ss;
}

// ---- fused prep: rmsnorm(x) (blocks 0..8191), weight casts (+gamma folds),
//      bias concat, sc zeroing (blocks 8192..) ----
__global__ __launch_bounds__(256) void k_prep(
    const float* __restrict__ x, const float* __restrict__ ng, f16* __restrict__ xn,
    const float* __restrict__ Wq_w, const float* __restrict__ Wkv_w,
    const float* __restrict__ W1_w, const float* __restrict__ g1,
    const float* __restrict__ W2_w, const float* __restrict__ g2,
    const float* __restrict__ Wq_b, const float* __restrict__ Wkv_b,
    f16* __restrict__ wqkv, f16* __restrict__ w1, f16* __restrict__ w2,
    float* __restrict__ cb, float* __restrict__ scz) {
    if (blockIdx.x < 8192) {
        size_t row = blockIdx.x;
        const float4 v = reinterpret_cast<const float4*>(x + row * 1024)[threadIdx.x];
        float ss = v.x * v.x + v.y * v.y + v.z * v.z + v.w * v.w;
        ss = blockReduceSum256(ss);
        float sc = 32.0f / fmaxf(sqrtf(ss), 1e-12f);
        const float4 g = reinterpret_cast<const float4*>(ng)[threadIdx.x];
        f16x4 o;
        o[0] = (f16)(v.x * sc * g.x); o[1] = (f16)(v.y * sc * g.y);
        o[2] = (f16)(v.z * sc * g.z); o[3] = (f16)(v.w * sc * g.w);
        *reinterpret_cast<f16x4*>(xn + row * 1024 + threadIdx.x * 4) = o;
        return;
    }
    int i = (blockIdx.x - 8192) * 256 + threadIdx.x;
    if (i < 1048576) {
        float4 v = reinterpret_cast<const float4*>(Wq_w)[i];
        f16x4 o; o[0] = (f16)v.x; o[1] = (f16)v.y; o[2] = (f16)v.z; o[3] = (f16)v.w;
        *reinterpret_cast<f16x4*>(wqkv + (size_t)i * 4) = o;
    } else if (i < 1310720) {
        int j = i - 1048576;
        float4 v = reinterpret_cast<const float4*>(Wkv_w)[j];
        f16x4 o; o[0] = (f16)v.x; o[1] = (f16)v.y; o[2] = (f16)v.z; o[3] = (f16)v.w;
        *reinterpret_cast<f16x4*>(wqkv + 4194304 + (size_t)j * 4) = o;
    } else if (i < 3407872) {
        int j = i - 1310720;
        float4 v = reinterpret_cast<const float4*>(W1_w)[j];
        int c = (j * 4) & 4095;
        f16x4 o;
        o[0] = (f16)(v.x * g1[c]);     o[1] = (f16)(v.y * g1[c + 1]);
        o[2] = (f16)(v.z * g1[c + 2]); o[3] = (f16)(v.w * g1[c + 3]);
        *reinterpret_cast<f16x4*>(w1 + (size_t)j * 4) = o;
    } else if (i < 3932160) {
        int j = i - 3407872;
        float4 v = reinterpret_cast<const float4*>(W2_w)[j];
        int c = (j * 4) & 2047;
        f16x4 o;
        o[0] = (f16)(v.x * g2[c]);     o[1] = (f16)(v.y * g2[c + 1]);
        o[2] = (f16)(v.z * g2[c + 2]); o[3] = (f16)(v.w * g2[c + 3]);
        *reinterpret_cast<f16x4*>(w2 + (size_t)j * 4) = o;
    } else if (i < 3933440) {
        int j = i - 3932160;
        int e = j * 4;
        float4 o4 = (e < 4096) ? reinterpret_cast<const float4*>(Wq_b)[j]
                               : reinterpret_cast<const float4*>(Wkv_b)[(e - 4096) >> 2];
        reinterpret_cast<float4*>(cb)[j] = o4;
    } else if (i < 3937536) {
        int j = i - 3933440;
        reinterpret_cast<float4*>(scz)[j] = make_float4(0.f, 0.f, 0.f, 0.f);
    }
}

// ==== 4-phase SGB-interleaved GEMM (16x16x32 MFMA), XCD-chunked mapping ====
// C[M,N] = (EPI>=1: rms(ssin)-scale) A[M,K]@Bt[N,K]^T + bias (+silu)
// EPI 0: f16 out. EPI 1: f16 out + scale/silu. EPI 2: f32 out + scale/silu.
template <int BN, int EPI>
__global__ __launch_bounds__(512, 2) void k_gemm8p(const f16* __restrict__ A,
                                                   const f16* __restrict__ Bt,
                                                   const float* __restrict__ bias,
                                                   const float* __restrict__ ssin,
                                                   float sqrtD,
                                                   void* __restrict__ Cout,
                                                   int M, int N, int K) {
    constexpr int BM = 256;
    constexpr int WN = BN / 64, WM = 8 / WN, WR = BM / WM;
    constexpr int MW = WR / 16, MH = MW / 2;
    constexpr int LA = 2, LB = BN / 128;
    constexpr int VS = 2 * LA + LB;
    constexpr int AK = BM * 32;
    constexpr int BKE = BN * 32;
    constexpr int SE = 2 * AK + 2 * BKE;

    __shared__ alignas(16) f16 lds[2 * SE];

    // XCD-chunked: all bn-blocks of one bm-stripe live in one XCD
    const int mb = M / BM;
    const int cpx = mb >> 3;
    const int xcd = blockIdx.x & 7;
    const int j = blockIdx.x >> 3;
    const int bm = xcd * cpx + (j % cpx);
    const int bn = j / cpx;

    const int tid = threadIdx.x, w = tid >> 6, l = tid & 63;
    const int wm = w / WN, wn = w % WN;
    const int lrow = l & 15, lq = l >> 4;
    const int g = (lrow >> 1) & 3;

    const f16* Ab = A + (size_t)bm * BM * K;
    const f16* Bb = Bt + (size_t)bn * BN * K;
    const int NT = K >> 6;

    int aoff[MW], boff[4];
#pragma unroll
    for (int m = 0; m < MW; ++m)
        aoff[m] = (wm * WR + m * 16 + lrow) * 32 + 8 * (lq ^ g);
#pragma unroll
    for (int n = 0; n < 4; ++n)
        boff[n] = (wn * 64 + n * 16 + lrow) * 32 + 8 * (lq ^ g);

    auto stageA = [&](int k0, f16* region) {
#pragma unroll
        for (int q = 0; q < LA; ++q) {
            int r = q * 128 + w * 16 + (l >> 2);
            int c = 8 * ((l & 3) ^ ((r >> 1) & 3));
            gload16(Ab + (size_t)r * K + k0 + c, region + q * 4096 + w * 512);
        }
    };
    auto stageB = [&](int k0, f16* region) {
#pragma unroll
        for (int q = 0; q < LB; ++q) {
            int r = q * 128 + w * 16 + (l >> 2);
            int c = 8 * ((l & 3) ^ ((r >> 1) & 3));
            gload16(Bb + (size_t)r * K + k0 + c, region + q * 4096 + w * 512);
        }
    };
    auto rdA = [&](f16x8 (&d)[MH], const f16* base, int h) {
#pragma unroll
        for (int m = 0; m < MH; ++m)
            d[m] = *reinterpret_cast<const f16x8*>(base + aoff[h * MH + m]);
    };
    auto rdB = [&](f16x8 (&d)[4], const f16* base) {
#pragma unroll
        for (int n = 0; n < 4; ++n)
            d[n] = *reinterpret_cast<const f16x8*>(base + boff[n]);
    };

    f32x4 acc[MW][4] = {};
    f16x8 afA[MH], afB[MH], bfA[4], bfB[4];

    auto mfmaLo = [&](f16x8 (&af)[MH], f16x8 (&bf)[4]) {
#pragma unroll
        for (int m = 0; m < MH; ++m)
#pragma unroll
            for (int n = 0; n < 4; ++n)
                acc[m][n] = MFMA16(af[m], bf[n], acc[m][n]);
    };
    auto mfmaHi = [&](f16x8 (&af)[MH], f16x8 (&bf)[4]) {
#pragma unroll
        for (int m = 0; m < MH; ++m)
#pragma unroll
            for (int n = 0; n < 4; ++n)
                acc[MH + m][n] = MFMA16(af[m], bf[n], acc[MH + m][n]);
    };

    // prologue
    stageA(0, lds);             stageB(0, lds + 2 * AK);
    stageA(32, lds + AK);       stageB(32, lds + 2 * AK + BKE);
    stageA(64, lds + SE);       stageB(64, lds + SE + 2 * AK);
    asm volatile("s_waitcnt vmcnt(%0)" :: "i"(2 * (LA + LB)) : "memory");
    __builtin_amdgcn_s_barrier();
    rdA(afA, lds, 0);
    rdB(bfA, lds + 2 * AK);

    const int NTm2 = NT - 2;
    for (int t = 0; t < NTm2; ++t) {
        f16* s0 = lds + (t & 1) * SE;
        f16* s1 = lds + ((t & 1) ^ 1) * SE;
        const int kn1 = (t + 1) << 6;
        const int kn2 = (t + 2) << 6;
        // ph0: MFMA(M0,kk0) | read af1_kk0 | stage A1(t+1)
        __builtin_amdgcn_s_barrier();
        stageA(kn1 + 32, s1 + AK);
        rdA(afB, s0, 1);
        mfmaLo(afA, bfA);
        sgb_phase<MH * 4, MH, LA>();
        // ph1: MFMA(M1,kk0) | read af0_kk1 + bf_kk1 | stage B1(t+1)
        asm volatile("s_waitcnt vmcnt(%0)" :: "i"(VS) : "memory");
        __builtin_amdgcn_s_barrier();
        stageB(kn1 + 32, s1 + 2 * AK + BKE);
        rdA(afA, s0 + AK, 0);
        rdB(bfB, s0 + 2 * AK + BKE);
        mfmaHi(afB, bfA);
        sgb_phase<MH * 4, MH + 4, LB>();
        // ph2: MFMA(M0,kk1) | read af1_kk1 | stage A0(t+2)
        __builtin_amdgcn_s_barrier();
        stageA(kn2, s0);
        rdA(afB, s0 + AK, 1);
        mfmaLo(afA, bfB);
        sgb_phase<MH * 4, MH, LA>();
        // ph3: MFMA(M1,kk1) | read af0_kk0(t+1) + bf_kk0(t+1) | stage B0(t+2)
        asm volatile("s_waitcnt vmcnt(%0)" :: "i"(VS) : "memory");
        __builtin_amdgcn_s_barrier();
        stageB(kn2, s0 + 2 * AK);
        rdA(afA, s1, 0);
        rdB(bfA, s1 + 2 * AK);
        mfmaHi(afB, bfB);
        sgb_phase<MH * 4, MH + 4, LB>();
    }
    // t = NT-2
    {
        const int t = NTm2;
        f16* s0 = lds + (t & 1) * SE;
        f16* s1 = lds + ((t & 1) ^ 1) * SE;
        const int kn1 = (t + 1) << 6;
        __builtin_amdgcn_s_barrier();
        stageA(kn1 + 32, s1 + AK);
        rdA(afB, s0, 1);
        mfmaLo(afA, bfA);
        sgb_phase<MH * 4, MH, LA>();
        asm volatile("s_waitcnt vmcnt(%0)" :: "i"(VS) : "memory");
        __builtin_amdgcn_s_barrier();
        stageB(kn1 + 32, s1 + 2 * AK + BKE);
        rdA(afA, s0 + AK, 0);
        rdB(bfB, s0 + 2 * AK + BKE);
        mfmaHi(afB, bfA);
        sgb_phase<MH * 4, MH + 4, LB>();
        __builtin_amdgcn_s_barrier();
        rdA(afB, s0 + AK, 1);
        mfmaLo(afA, bfB);
        sgb_phase<MH * 4, MH, 0>();
        asm volatile("s_waitcnt vmcnt(%0)" :: "i"(LA + LB) : "memory");
        __builtin_amdgcn_s_barrier();
        rdA(afA, s1, 0);
        rdB(bfA, s1 + 2 * AK);
        mfmaHi(afB, bfB);
        sgb_phase<MH * 4, MH + 4, 0>();
    }
    // t = NT-1
    {
        f16* s0 = lds + ((NT - 1) & 1) * SE;
        __builtin_amdgcn_s_barrier();
        rdA(afB, s0, 1);
        mfmaLo(afA, bfA);
        sgb_phase<MH * 4, MH, 0>();
        asm volatile("s_waitcnt vmcnt(0)" ::: "memory");
        __builtin_amdgcn_s_barrier();
        rdA(afA, s0 + AK, 0);
        rdB(bfB, s0 + 2 * AK + BKE);
        mfmaHi(afB, bfA);
        sgb_phase<MH * 4, MH + 4, 0>();
        __builtin_amdgcn_s_barrier();
        rdA(afB, s0 + AK, 1);
        mfmaLo(afA, bfB);
        sgb_phase<MH * 4, MH, 0>();
        mfmaHi(afB, bfB);
    }

    // epilogue
    const size_t row0 = (size_t)bm * BM + wm * WR;
    const int col0 = bn * BN + wn * 64;
    float bsv[4];
#pragma unroll
    for (int n = 0; n < 4; ++n) bsv[n] = bias[col0 + n * 16 + lrow];
#pragma unroll
    for (int m = 0; m < MW; ++m) {
#pragma unroll
        for (int r = 0; r < 4; ++r) {
            const size_t row = row0 + m * 16 + lq * 4 + r;
            float scl = 1.0f;
            if (EPI >= 1) scl = sqrtD * rsqrtf(fmaxf(ssin[row], 1e-24f));
#pragma unroll
            for (int n = 0; n < 4; ++n) {
                float v = acc[m][n][r];
                if (EPI >= 1) v = v * scl;
                v += bsv[n];
                if (EPI >= 1) v = v / (1.f + __expf(-v));
                const size_t idx = row * (size_t)N + col0 + n * 16 + lrow;
                if (EPI == 2) reinterpret_cast<float*>(Cout)[idx] = v;
                else          reinterpret_cast<f16*>(Cout)[idx] = (f16)v;
            }
        }
    }
}

// ---- windowed GQA attention from combined QKV buffer (row stride 5120) ----
// also accumulates per-row sum of squares of output into ssout (pre-zeroed)
__global__ __launch_bounds__(256) void k_attn(const f16* __restrict__ qkv,
                                              f16* __restrict__ o,
                                              float* __restrict__ ssout) {
    __shared__ alignas(16) f16 Ksm[64 * 64];
    __shared__ alignas(16) f16 Vtsm[64 * 64];
    __shared__ alignas(16) f16 Psm[4][64 * 64];
    const int idx = blockIdx.x;
    const int s = idx & 127;
    const int g = (idx >> 7) & 7;
    const int b = idx >> 10;
    const int tid = threadIdx.x;
    const int w = tid >> 6, l = tid & 63;

    const int baseR = s * 32 - 16;
#pragma unroll
    for (int i = 0; i < 2; ++i) {
        const int j = i * 32 + (tid >> 3);
        const int d0 = (tid & 7) * 8;
        const int R = baseR + j;
        f16x8 kvv = {}, vvv = {};
        if (R >= 0 && R < 4096) {
            const f16* rp = qkv + ((size_t)(b * 4096 + R)) * 5120 + 4096 + g * 64 + d0;
            kvv = *reinterpret_cast<const f16x8*>(rp);
            vvv = *reinterpret_cast<const f16x8*>(rp + 512);
        }
        *reinterpret_cast<f16x8*>(&Ksm[j * 64 + d0]) = kvv;
#pragma unroll
        for (int e = 0; e < 8; ++e) Vtsm[(d0 + e) * 64 + j] = vvv[e];
    }

    const int lrow = l & 15, lk = (l >> 4) * 8;
    f16x8 aq[4][2];
#pragma unroll
    for (int m = 0; m < 4; ++m) {
        const int qr = w * 64 + m * 16 + lrow;
        const int h = qr >> 5, qi = qr & 31;
        const f16* qp = qkv + ((size_t)(b * 4096 + s * 32 + qi)) * 5120 + (g * 8 + h) * 64 + lk;
        aq[m][0] = *reinterpret_cast<const f16x8*>(qp);
        aq[m][1] = *reinterpret_cast<const f16x8*>(qp + 32);
    }
    __syncthreads();

    f32x4 acc[4][4] = {};
#pragma unroll
    for (int kk = 0; kk < 2; ++kk) {
        f16x8 bk[4];
#pragma unroll
        for (int n = 0; n < 4; ++n)
            bk[n] = *reinterpret_cast<const f16x8*>(&Ksm[(n * 16 + lrow) * 64 + kk * 32 + lk]);
#pragma unroll
        for (int m = 0; m < 4; ++m)
#pragma unroll
            for (int n = 0; n < 4; ++n)
                acc[m][n] = MFMA16(aq[m][kk], bk[n], acc[m][n]);
    }

    const int nlo = (s == 0) ? 1 : 0;
    const int nhi = (s == 127) ? 3 : 4;
#pragma unroll
    for (int m = 0; m < 4; ++m) {
#pragma unroll
        for (int r = 0; r < 4; ++r) {
            float xv[4];
#pragma unroll
            for (int n = 0; n < 4; ++n) xv[n] = acc[m][n][r] * 0.125f;
            float mx = -1e30f;
            for (int n = nlo; n < nhi; ++n) mx = fmaxf(mx, xv[n]);
#pragma unroll
            for (int off = 8; off > 0; off >>= 1) mx = fmaxf(mx, __shfl_xor(mx, off));
            float pv[4]; float sum = 0.f;
#pragma unroll
            for (int n = 0; n < 4; ++n) {
                float e = (n >= nlo && n < nhi) ? __expf(xv[n] - mx) : 0.f;
                pv[n] = e; sum += e;
            }
#pragma unroll
            for (int off = 8; off > 0; off >>= 1) sum += __shfl_xor(sum, off);
            const float inv = 1.f / sum;
            const int prow = m * 16 + (l >> 4) * 4 + r;
#pragma unroll
            for (int n = 0; n < 4; ++n)
                Psm[w][prow * 64 + n * 16 + lrow] = (f16)(pv[n] * inv);
        }
    }
    __syncthreads();

    f32x4 oacc[4][4] = {};
#pragma unroll
    for (int kk = 0; kk < 2; ++kk) {
        f16x8 ap[4], bv[4];
#pragma unroll
        for (int m = 0; m < 4; ++m)
            ap[m] = *reinterpret_cast<const f16x8*>(&Psm[w][(m * 16 + lrow) * 64 + kk * 32 + lk]);
#pragma unroll
        for (int n = 0; n < 4; ++n)
            bv[n] = *reinterpret_cast<const f16x8*>(&Vtsm[(n * 16 + lrow) * 64 + kk * 32 + lk]);
#pragma unroll
        for (int m = 0; m < 4; ++m)
#pragma unroll
            for (int n = 0; n < 4; ++n)
                oacc[m][n] = MFMA16(ap[m], bv[n], oacc[m][n]);
    }
    const int lr4 = (l >> 4) * 4;
#pragma unroll
    for (int m = 0; m < 4; ++m) {
#pragma unroll
        for (int r = 0; r < 4; ++r) {
            const int qr = w * 64 + m * 16 + lr4 + r;
            const int h = qr >> 5, qi = qr & 31;
            f16* op = o + ((size_t)(b * 4096 + s * 32 + qi)) * 4096 + (g * 8 + h) * 64;
            float ssp = 0.f;
#pragma unroll
            for (int n = 0; n < 4; ++n) {
                float v = oacc[m][n][r];
                op[n * 16 + lrow] = (f16)v;
                ssp += v * v;
            }
            ssp += __shfl_xor(ssp, 1);
            ssp += __shfl_xor(ssp, 2);
            ssp += __shfl_xor(ssp, 4);
            ssp += __shfl_xor(ssp, 8);
            if (lrow == 0)
                atomicAdd(&ssout[(size_t)(b * 4096 + s * 32 + qi)], ssp);
        }
    }
}

extern "C" void kernel_launch(void* const* d_in, const int* in_sizes, int n_in,
                              void* d_out, int out_size, void* d_ws, size_t ws_size,
                              hipStream_t stream) {
    const float* x     = (const float*)d_in[0];
    const float* ng    = (const float*)d_in[1];
    const float* Wq_w  = (const float*)d_in[2];
    const float* Wq_b  = (const float*)d_in[3];
    const float* Wkv_w = (const float*)d_in[4];
    const float* Wkv_b = (const float*)d_in[5];
    const float* g1    = (const float*)d_in[6];
    const float* W1_w  = (const float*)d_in[7];
    const float* W1_b  = (const float*)d_in[8];
    const float* g2    = (const float*)d_in[9];
    const float* W2_w  = (const float*)d_in[10];
    const float* W2_b  = (const float*)d_in[11];
    float* out = (float*)d_out;

    char* p = (char*)d_ws;
    f16* qkv  = (f16*)(p);                 // [8192][5120] 80 MB
    f16* h1   = (f16*)(p);                 // [8192][2048] (over qkv, after attn)
    f16* xn   = (f16*)(p + 83886080);      // [8192][1024]
    f16* ob   = (f16*)(p + 83886080);      // [8192][4096] (over xn, written by attn)
    f16* w1   = (f16*)(p + 150994944);     // 16 MB
    f16* w2   = (f16*)(p + 167772160);     // 4 MB
    f16* wqkv = (f16*)(p + 171966464);     // [5120][1024] 10 MB
    float* cb  = (float*)(p + 182452224);  // [5120]
    float* sc1 = (float*)(p + 182472704);  // [8192]
    float* sc2 = (float*)(p + 182505472);  // [8192]

    // fused prep: rmsnorm(x) + weight casts (+gamma folds) + bias concat + sc1 zero
    k_prep<<<8192 + 15381, 256, 0, stream>>>(x, ng, xn,
                                             Wq_w, Wkv_w, W1_w, g1, W2_w, g2,
                                             Wq_b, Wkv_b, wqkv, w1, w2, cb, sc1);

    // QKV: [8192,1024] @ [5120,1024]^T -> [8192,5120]
    k_gemm8p<256, 0><<<640, 512, 0, stream>>>(xn, wqkv, cb, nullptr, 0.f,
                                              qkv, 8192, 5120, 1024);

    // attention (writes ob, accumulates sc1 = per-row ss of ob)
    k_attn<<<2048, 256, 0, stream>>>(qkv, ob, sc1);

    // FF1: silu(scl(sc1)*(ob @ (g1.W1)^T) + b1) -> h1
    k_gemm8p<256, 1><<<256, 512, 0, stream>>>(ob, w1, W1_b, sc1, 64.0f,
                                              h1, 8192, 2048, 4096);
    k_rowss<2048><<<8192, 256, 0, stream>>>(h1, sc2);
    // FF2: silu(scl(sc2)*(h1 @ (g2.W2)^T) + b2) -> out f32
    k_gemm8p<128, 2><<<256, 512, 0, stream>>>(h1, w2, W2_b, sc2, 45.254834f,
                                              (void*)out, 8192, 1024, 2048);

    (void)in_sizes; (void)n_in; (void)out_size; (void)ws_size;
}